// Round 1
// baseline (505.715 us; speedup 1.0000x reference)
//
#include <hip/hip_runtime.h>
#include <hip/hip_bf16.h>
#include <math.h>

#define B_ 1024
#define S_ 512
#define E_ 1024
#define D_ 2048
#define SMOOTH 10.0f

// ---------------- reduction helpers ----------------
__inline__ __device__ float waveReduceMax(float v) {
#pragma unroll
    for (int o = 32; o; o >>= 1) v = fmaxf(v, __shfl_xor(v, o));
    return v;
}
__inline__ __device__ float waveReduceSum(float v) {
#pragma unroll
    for (int o = 32; o; o >>= 1) v += __shfl_xor(v, o);
    return v;
}

// ---------------- GEMM: C = A(MxK,row) @ B(KxN,row), optional per-k scale on B rows ----------------
// 64x64 tile, BK=16, 256 threads, 4x4 acc per thread.
__global__ __launch_bounds__(256) void gemm_nn(const float* __restrict__ A,
                                               const float* __restrict__ B,
                                               const float* __restrict__ bscale,
                                               float* __restrict__ C,
                                               int M, int N, int K) {
    __shared__ float As[16][65];
    __shared__ float Bs[16][65];
    const int tid = threadIdx.x;
    const int bm = blockIdx.y * 64, bn = blockIdx.x * 64;
    const int tx = tid & 15, ty = tid >> 4;
    float acc[4][4] = {};
    for (int kt = 0; kt < K; kt += 16) {
        {   // A tile: 64 rows x 16 k
            int k = tid & 15;
            int r0 = tid >> 4;
#pragma unroll
            for (int i = 0; i < 4; i++) {
                int r = r0 + i * 16;
                As[k][r] = A[(size_t)(bm + r) * K + kt + k];
            }
        }
        {   // B tile: 16 k x 64 cols
            int c = tid & 63;
            int r0 = tid >> 6;
#pragma unroll
            for (int i = 0; i < 4; i++) {
                int r = r0 + i * 4;
                float v = B[(size_t)(kt + r) * N + bn + c];
                if (bscale) v *= bscale[kt + r];
                Bs[r][c] = v;
            }
        }
        __syncthreads();
#pragma unroll
        for (int kk = 0; kk < 16; kk++) {
            float a[4], b[4];
#pragma unroll
            for (int i = 0; i < 4; i++) a[i] = As[kk][ty * 4 + i];
#pragma unroll
            for (int j = 0; j < 4; j++) b[j] = Bs[kk][tx * 4 + j];
#pragma unroll
            for (int i = 0; i < 4; i++)
#pragma unroll
                for (int j = 0; j < 4; j++) acc[i][j] += a[i] * b[j];
        }
        __syncthreads();
    }
#pragma unroll
    for (int i = 0; i < 4; i++)
#pragma unroll
        for (int j = 0; j < 4; j++)
            C[(size_t)(bm + ty * 4 + i) * N + bn + tx * 4 + j] = acc[i][j];
}

// ---------------- GEMM: C = A(MxK,row) @ B(NxK,row)^T ----------------
__global__ __launch_bounds__(256) void gemm_nt(const float* __restrict__ A,
                                               const float* __restrict__ B,
                                               float* __restrict__ C,
                                               int M, int N, int K) {
    __shared__ float As[16][65];
    __shared__ float Bs[16][65];
    const int tid = threadIdx.x;
    const int bm = blockIdx.y * 64, bn = blockIdx.x * 64;
    const int tx = tid & 15, ty = tid >> 4;
    float acc[4][4] = {};
    for (int kt = 0; kt < K; kt += 16) {
        {
            int k = tid & 15;
            int r0 = tid >> 4;
#pragma unroll
            for (int i = 0; i < 4; i++) {
                int r = r0 + i * 16;
                As[k][r] = A[(size_t)(bm + r) * K + kt + k];
                Bs[k][r] = B[(size_t)(bn + r) * K + kt + k];
            }
        }
        __syncthreads();
#pragma unroll
        for (int kk = 0; kk < 16; kk++) {
            float a[4], b[4];
#pragma unroll
            for (int i = 0; i < 4; i++) a[i] = As[kk][ty * 4 + i];
#pragma unroll
            for (int j = 0; j < 4; j++) b[j] = Bs[kk][tx * 4 + j];
#pragma unroll
            for (int i = 0; i < 4; i++)
#pragma unroll
                for (int j = 0; j < 4; j++) acc[i][j] += a[i] * b[j];
        }
        __syncthreads();
    }
#pragma unroll
    for (int i = 0; i < 4; i++)
#pragma unroll
        for (int j = 0; j < 4; j++)
            C[(size_t)(bm + ty * 4 + i) * N + bn + tx * 4 + j] = acc[i][j];
}

// ---------------- BN partial sums (per column over rows) ----------------
__global__ __launch_bounds__(256) void bn_partial(const float* __restrict__ Z,
                                                  int rows_per,
                                                  float* __restrict__ sums, int E) {
    int c = blockIdx.x * 256 + threadIdx.x;
    int r0 = blockIdx.y * rows_per;
    float s = 0.f, ss = 0.f;
    for (int r = r0; r < r0 + rows_per; r++) {
        float v = Z[(size_t)r * E + c];
        s += v;
        ss += v * v;
    }
    atomicAdd(&sums[c], s);
    atomicAdd(&sums[E + c], ss);
}

// ---------------- BN finalize + tanh (+ optional column scale) ----------------
__global__ __launch_bounds__(256) void bn_apply(const float* __restrict__ Z,
                                                const float* __restrict__ sums,
                                                const float* __restrict__ g,
                                                const float* __restrict__ b,
                                                const float* __restrict__ scale,
                                                float* __restrict__ W, int R, int E) {
    int idx = blockIdx.x * 256 + threadIdx.x;
    int c = idx & (E - 1);
    float invR = 1.0f / (float)R;
    float mu = sums[c] * invR;
    float var = sums[E + c] * invR - mu * mu;
    float rstd = rsqrtf(var + 1e-5f);
    float z = Z[idx];
    float w = tanhf(g[c] * (z - mu) * rstd + b[c]);
    if (scale) w *= scale[c];
    W[idx] = w;
}

// ---------------- row softmax (n=512, block=256) ----------------
__global__ __launch_bounds__(256) void softmax_rows(const float* __restrict__ A,
                                                    float* __restrict__ O, int n) {
    __shared__ float red[4];
    int row = blockIdx.x;
    const float* a = A + (size_t)row * n;
    int t = threadIdx.x;
    float v0 = a[t] * SMOOTH;
    float v1 = a[t + 256] * SMOOTH;
    float m = waveReduceMax(fmaxf(v0, v1));
    if ((t & 63) == 0) red[t >> 6] = m;
    __syncthreads();
    m = fmaxf(fmaxf(red[0], red[1]), fmaxf(red[2], red[3]));
    float e0 = __expf(v0 - m), e1 = __expf(v1 - m);
    float s = waveReduceSum(e0 + e1);
    __syncthreads();
    if ((t & 63) == 0) red[t >> 6] = s;
    __syncthreads();
    s = red[0] + red[1] + red[2] + red[3];
    float inv = 1.0f / s;
    O[(size_t)row * n + t] = e0 * inv;
    O[(size_t)row * n + t + 256] = e1 * inv;
}

// ---------------- per-row inverse norm of concept_feature ----------------
__global__ __launch_bounds__(256) void row_invnorm(const float* __restrict__ X,
                                                   float* __restrict__ inv, int n) {
    __shared__ float red[4];
    int row = blockIdx.x;
    const float* x = X + (size_t)row * n;
    float ss = 0.f;
    for (int i = threadIdx.x; i < n; i += 256) {
        float v = x[i];
        ss += v * v;
    }
    ss = waveReduceSum(ss);
    if ((threadIdx.x & 63) == 0) red[threadIdx.x >> 6] = ss;
    __syncthreads();
    ss = red[0] + red[1] + red[2] + red[3];
    if (threadIdx.x == 0) inv[row] = 1.0f / (sqrtf(ss) + 1e-8f);
}

// ---------------- row l2norm -> output ----------------
__global__ __launch_bounds__(256) void rownorm_out(const float* __restrict__ X,
                                                   float* __restrict__ O, int n) {
    __shared__ float red[4];
    int row = blockIdx.x;
    const float* x = X + (size_t)row * n;
    float ss = 0.f;
    for (int i = threadIdx.x; i < n; i += 256) {
        float v = x[i];
        ss += v * v;
    }
    ss = waveReduceSum(ss);
    if ((threadIdx.x & 63) == 0) red[threadIdx.x >> 6] = ss;
    __syncthreads();
    ss = red[0] + red[1] + red[2] + red[3];
    float s = 1.0f / (sqrtf(ss) + 1e-8f);
    for (int i = threadIdx.x; i < n; i += 256)
        O[(size_t)row * n + i] = x[i] * s;
}

extern "C" void kernel_launch(void* const* d_in, const int* in_sizes, int n_in,
                              void* d_out, int out_size, void* d_ws, size_t ws_size,
                              hipStream_t stream) {
    const float* emb   = (const float*)d_in[0];   // (B,E)
    const float* cf    = (const float*)d_in[1];   // (S,D)
    const float* fc1_w = (const float*)d_in[3];   // (D,E)
    const float* bn1_g = (const float*)d_in[5];
    const float* bn1_b = (const float*)d_in[6];
    const float* fc2_w = (const float*)d_in[7];   // (E,E)
    const float* bn2_g = (const float*)d_in[9];
    const float* bn2_b = (const float*)d_in[10];
    const float* fc3_w = (const float*)d_in[11];  // (E,)

    float* out = (float*)d_out;
    float* emb_concept = out;                       // B*D
    float* weights_v   = out + (size_t)B_ * D_;     // B*S

    float* ws = (float*)d_ws;
    float* Z1      = ws;                            // S*E
    float* W_s     = Z1 + (size_t)S_ * E_;          // S*E
    float* Z2      = W_s + (size_t)S_ * E_;         // B*E
    float* Wv3     = Z2 + (size_t)B_ * E_;          // B*E
    float* a_s     = Wv3 + (size_t)B_ * E_;         // B*S
    float* emb_pre = a_s + (size_t)B_ * S_;         // B*D
    float* sums1   = emb_pre + (size_t)B_ * D_;     // 2*E
    float* sums2   = sums1 + 2 * E_;                // 2*E
    float* invn    = sums2 + 2 * E_;                // S

    // zero BN accumulators (sums1 and sums2 contiguous: 4*E floats)
    hipMemsetAsync(sums1, 0, 4 * E_ * sizeof(float), stream);

    // branch 1: W_s = bn_tanh(cf @ fc1_w)   (bias cancels in BN)
    gemm_nn<<<dim3(E_ / 64, S_ / 64), 256, 0, stream>>>(cf, fc1_w, nullptr, Z1, S_, E_, D_);
    bn_partial<<<dim3(E_ / 256, 16), 256, 0, stream>>>(Z1, S_ / 16, sums1, E_);
    bn_apply<<<dim3((S_ * E_) / 256), 256, 0, stream>>>(Z1, sums1, bn1_g, bn1_b, nullptr, W_s, S_, E_);

    // branch 2: Wv3 = bn_tanh(emb @ fc2_w) * fc3_w
    gemm_nn<<<dim3(E_ / 64, B_ / 64), 256, 0, stream>>>(emb, fc2_w, nullptr, Z2, B_, E_, E_);
    bn_partial<<<dim3(E_ / 256, 16), 256, 0, stream>>>(Z2, B_ / 16, sums2, E_);
    bn_apply<<<dim3((B_ * E_) / 256), 256, 0, stream>>>(Z2, sums2, bn2_g, bn2_b, fc3_w, Wv3, B_, E_);

    // a_s = Wv3 @ W_s^T  (fc3_b cancels in softmax)
    gemm_nt<<<dim3(S_ / 64, B_ / 64), 256, 0, stream>>>(Wv3, W_s, a_s, B_, S_, E_);

    // weights_v = softmax(a_s * SMOOTH)
    softmax_rows<<<dim3(B_), 256, 0, stream>>>(a_s, weights_v, S_);

    // emb_concept = l2norm( (weights_v * invnorm) @ cf )
    row_invnorm<<<dim3(S_), 256, 0, stream>>>(cf, invn, D_);
    gemm_nn<<<dim3(D_ / 64, B_ / 64), 256, 0, stream>>>(weights_v, cf, invn, emb_pre, B_, D_, S_);
    rownorm_out<<<dim3(B_), 256, 0, stream>>>(emb_pre, emb_concept, D_);
}

// Round 2
// 222.494 us; speedup vs baseline: 2.2729x; 2.2729x over previous
//
#include <hip/hip_runtime.h>
#include <hip/hip_bf16.h>
#include <math.h>

#define B_ 1024
#define S_ 512
#define E_ 1024
#define D_ 2048
#define SMOOTH 10.0f

typedef __attribute__((ext_vector_type(8))) short bf16x8;
typedef __attribute__((ext_vector_type(4))) float f32x4;

__device__ __forceinline__ short f2bf(float f) {
    __hip_bfloat16 h = __float2bfloat16(f);
    short s; __builtin_memcpy(&s, &h, 2); return s;
}
__device__ __forceinline__ float bf2f(short s) {
    __hip_bfloat16 h; __builtin_memcpy(&h, &s, 2);
    return __bfloat162float(h);
}

// ---------------- reduction helpers ----------------
__inline__ __device__ float waveReduceMax(float v) {
#pragma unroll
    for (int o = 32; o; o >>= 1) v = fmaxf(v, __shfl_xor(v, o));
    return v;
}
__inline__ __device__ float waveReduceSum(float v) {
#pragma unroll
    for (int o = 32; o; o >>= 1) v += __shfl_xor(v, o);
    return v;
}

// ---------------- split conversion: x -> hi + lo (bf16 pair) ----------------
__global__ __launch_bounds__(256) void split_cvt(const float* __restrict__ x,
                                                 short* __restrict__ hi,
                                                 short* __restrict__ lo, int n4) {
    int i = (blockIdx.x * 256 + threadIdx.x) * 4;
#pragma unroll
    for (int j = 0; j < 4; j++) {
        float v = x[i + j];
        short h = f2bf(v);
        hi[i + j] = h;
        lo[i + j] = f2bf(v - bf2f(h));
    }
}

// ---------------- transpose + split: out[c][r] = in[r][c] ----------------
__global__ __launch_bounds__(256) void split_cvt_T(const float* __restrict__ in,
                                                   short* __restrict__ hi,
                                                   short* __restrict__ lo,
                                                   int R, int C) {
    __shared__ float t[32][33];
    int c0 = blockIdx.x * 32, r0 = blockIdx.y * 32;
    int cx = threadIdx.x & 31, ry0 = threadIdx.x >> 5;
#pragma unroll
    for (int i = 0; i < 4; i++) {
        int ry = ry0 + i * 8;
        t[ry][cx] = in[(size_t)(r0 + ry) * C + c0 + cx];
    }
    __syncthreads();
    int rx = threadIdx.x & 31, cy0 = threadIdx.x >> 5;
#pragma unroll
    for (int i = 0; i < 4; i++) {
        int cy = cy0 + i * 8;
        float v = t[rx][cy];
        size_t o = (size_t)(c0 + cy) * R + r0 + rx;
        short h = f2bf(v);
        hi[o] = h;
        lo[o] = f2bf(v - bf2f(h));
    }
}

// ---------------- transpose + scale rows + single bf16 ----------------
__global__ __launch_bounds__(256) void cvt_T_scale(const float* __restrict__ in,
                                                   const float* __restrict__ rowscale,
                                                   short* __restrict__ out,
                                                   int R, int C) {
    __shared__ float t[32][33];
    int c0 = blockIdx.x * 32, r0 = blockIdx.y * 32;
    int cx = threadIdx.x & 31, ry0 = threadIdx.x >> 5;
#pragma unroll
    for (int i = 0; i < 4; i++) {
        int ry = ry0 + i * 8;
        t[ry][cx] = in[(size_t)(r0 + ry) * C + c0 + cx] * rowscale[r0 + ry];
    }
    __syncthreads();
    int rx = threadIdx.x & 31, cy0 = threadIdx.x >> 5;
#pragma unroll
    for (int i = 0; i < 4; i++) {
        int cy = cy0 + i * 8;
        out[(size_t)(c0 + cy) * R + r0 + rx] = f2bf(t[rx][cy]);
    }
}

// ---------------- MFMA GEMM, nt form: C(MxN) = A(MxK) @ B(NxK)^T ----------------
// 64x64 block tile, 4 waves (2x2), each wave 32x32 (2x2 frags of 16x16x32).
// SPLIT: 3-term hi/lo product for ~fp32 accuracy.
template<bool SPLIT>
__global__ __launch_bounds__(256) void gemm_mfma_nt(const short* __restrict__ Ahi,
                                                    const short* __restrict__ Alo,
                                                    const short* __restrict__ Bhi,
                                                    const short* __restrict__ Blo,
                                                    float* __restrict__ C,
                                                    int M, int N, int K) {
    const int tid = threadIdx.x;
    const int wid = tid >> 6, lane = tid & 63;
    const int wr = wid >> 1, wc = wid & 1;
    const int bm = blockIdx.y * 64, bn = blockIdx.x * 64;
    const int r16 = lane & 15, kg = lane >> 4;

    const size_t aoff0 = (size_t)(bm + wr * 32 + r16) * K + kg * 8;
    const size_t aoff1 = aoff0 + (size_t)16 * K;
    const size_t boff0 = (size_t)(bn + wc * 32 + r16) * K + kg * 8;
    const size_t boff1 = boff0 + (size_t)16 * K;

    f32x4 acc[2][2] = {};

#pragma unroll 2
    for (int k0 = 0; k0 < K; k0 += 32) {
        bf16x8 ah[2], bh[2];
        ah[0] = *(const bf16x8*)(Ahi + aoff0 + k0);
        ah[1] = *(const bf16x8*)(Ahi + aoff1 + k0);
        bh[0] = *(const bf16x8*)(Bhi + boff0 + k0);
        bh[1] = *(const bf16x8*)(Bhi + boff1 + k0);
#pragma unroll
        for (int m = 0; m < 2; m++)
#pragma unroll
            for (int n = 0; n < 2; n++)
                acc[m][n] = __builtin_amdgcn_mfma_f32_16x16x32_bf16(ah[m], bh[n], acc[m][n], 0, 0, 0);
        if (SPLIT) {
            bf16x8 al[2], bl[2];
            al[0] = *(const bf16x8*)(Alo + aoff0 + k0);
            al[1] = *(const bf16x8*)(Alo + aoff1 + k0);
            bl[0] = *(const bf16x8*)(Blo + boff0 + k0);
            bl[1] = *(const bf16x8*)(Blo + boff1 + k0);
#pragma unroll
            for (int m = 0; m < 2; m++)
#pragma unroll
                for (int n = 0; n < 2; n++) {
                    acc[m][n] = __builtin_amdgcn_mfma_f32_16x16x32_bf16(ah[m], bl[n], acc[m][n], 0, 0, 0);
                    acc[m][n] = __builtin_amdgcn_mfma_f32_16x16x32_bf16(al[m], bh[n], acc[m][n], 0, 0, 0);
                }
        }
    }

#pragma unroll
    for (int m = 0; m < 2; m++)
#pragma unroll
        for (int n = 0; n < 2; n++) {
            int col = bn + wc * 32 + n * 16 + r16;
#pragma unroll
            for (int r = 0; r < 4; r++) {
                int row = bm + wr * 32 + m * 16 + kg * 4 + r;
                C[(size_t)row * N + col] = acc[m][n][r];
            }
        }
}

// ---------------- BN partial sums ----------------
__global__ __launch_bounds__(256) void bn_partial(const float* __restrict__ Z,
                                                  int rows_per,
                                                  float* __restrict__ sums, int E) {
    int c = blockIdx.x * 256 + threadIdx.x;
    int r0 = blockIdx.y * rows_per;
    float s = 0.f, ss = 0.f;
    for (int r = r0; r < r0 + rows_per; r++) {
        float v = Z[(size_t)r * E + c];
        s += v;
        ss += v * v;
    }
    atomicAdd(&sums[c], s);
    atomicAdd(&sums[E + c], ss);
}

// ---------------- BN finalize + tanh (+ scale) -> bf16 hi/lo ----------------
__global__ __launch_bounds__(256) void bn_apply_split(const float* __restrict__ Z,
                                                      const float* __restrict__ sums,
                                                      const float* __restrict__ g,
                                                      const float* __restrict__ b,
                                                      const float* __restrict__ scale,
                                                      short* __restrict__ Whi,
                                                      short* __restrict__ Wlo,
                                                      int R, int E) {
    int idx = blockIdx.x * 256 + threadIdx.x;
    int c = idx & (E - 1);
    float invR = 1.0f / (float)R;
    float mu = sums[c] * invR;
    float var = sums[E + c] * invR - mu * mu;
    float rstd = rsqrtf(var + 1e-5f);
    float w = tanhf(g[c] * (Z[idx] - mu) * rstd + b[c]);
    if (scale) w *= scale[c];
    short h = f2bf(w);
    Whi[idx] = h;
    Wlo[idx] = f2bf(w - bf2f(h));
}

// ---------------- row softmax (n=512), writes fp32 + bf16 ----------------
__global__ __launch_bounds__(256) void softmax_rows(const float* __restrict__ A,
                                                    float* __restrict__ O,
                                                    short* __restrict__ O16, int n) {
    __shared__ float red[4];
    int row = blockIdx.x;
    const float* a = A + (size_t)row * n;
    int t = threadIdx.x;
    float v0 = a[t] * SMOOTH;
    float v1 = a[t + 256] * SMOOTH;
    float m = waveReduceMax(fmaxf(v0, v1));
    if ((t & 63) == 0) red[t >> 6] = m;
    __syncthreads();
    m = fmaxf(fmaxf(red[0], red[1]), fmaxf(red[2], red[3]));
    float e0 = __expf(v0 - m), e1 = __expf(v1 - m);
    float s = waveReduceSum(e0 + e1);
    __syncthreads();
    if ((t & 63) == 0) red[t >> 6] = s;
    __syncthreads();
    s = red[0] + red[1] + red[2] + red[3];
    float inv = 1.0f / s;
    float w0 = e0 * inv, w1 = e1 * inv;
    O[(size_t)row * n + t] = w0;
    O[(size_t)row * n + t + 256] = w1;
    O16[(size_t)row * n + t] = f2bf(w0);
    O16[(size_t)row * n + t + 256] = f2bf(w1);
}

// ---------------- per-row inverse norm ----------------
__global__ __launch_bounds__(256) void row_invnorm(const float* __restrict__ X,
                                                   float* __restrict__ inv, int n) {
    __shared__ float red[4];
    int row = blockIdx.x;
    const float* x = X + (size_t)row * n;
    float ss = 0.f;
    for (int i = threadIdx.x; i < n; i += 256) {
        float v = x[i];
        ss += v * v;
    }
    ss = waveReduceSum(ss);
    if ((threadIdx.x & 63) == 0) red[threadIdx.x >> 6] = ss;
    __syncthreads();
    ss = red[0] + red[1] + red[2] + red[3];
    if (threadIdx.x == 0) inv[row] = 1.0f / (sqrtf(ss) + 1e-8f);
}

// ---------------- row l2norm (in-place safe) ----------------
__global__ __launch_bounds__(256) void rownorm_out(const float* __restrict__ X,
                                                   float* __restrict__ O, int n) {
    __shared__ float red[4];
    int row = blockIdx.x;
    const float* x = X + (size_t)row * n;
    float ss = 0.f;
    for (int i = threadIdx.x; i < n; i += 256) {
        float v = x[i];
        ss += v * v;
    }
    ss = waveReduceSum(ss);
    if ((threadIdx.x & 63) == 0) red[threadIdx.x >> 6] = ss;
    __syncthreads();
    ss = red[0] + red[1] + red[2] + red[3];
    float s = 1.0f / (sqrtf(ss) + 1e-8f);
    for (int i = threadIdx.x; i < n; i += 256)
        O[(size_t)row * n + i] = x[i] * s;
}

extern "C" void kernel_launch(void* const* d_in, const int* in_sizes, int n_in,
                              void* d_out, int out_size, void* d_ws, size_t ws_size,
                              hipStream_t stream) {
    const float* emb   = (const float*)d_in[0];   // (B,E)
    const float* cf    = (const float*)d_in[1];   // (S,D)
    const float* fc1_w = (const float*)d_in[3];   // (D,E)
    const float* bn1_g = (const float*)d_in[5];
    const float* bn1_b = (const float*)d_in[6];
    const float* fc2_w = (const float*)d_in[7];   // (E,E)
    const float* bn2_g = (const float*)d_in[9];
    const float* bn2_b = (const float*)d_in[10];
    const float* fc3_w = (const float*)d_in[11];  // (E,)

    float* out = (float*)d_out;
    float* emb_concept = out;                     // B*D (pre-norm written here, normalized in place)
    float* weights_v   = out + (size_t)B_ * D_;   // B*S

    const size_t MB = 1024 * 1024;
    char* w = (char*)d_ws;
    // [0,8MB): phase A = Bt1 hi/lo; phase B = A2 hi/lo + Bt2 hi/lo; phase C = cfTn + A4
    short* Bt1hi = (short*)(w + 0 * MB);          // E*D shorts = 4MB
    short* Bt1lo = (short*)(w + 4 * MB);
    short* A2hi  = (short*)(w + 0 * MB);          // B*E shorts = 2MB
    short* A2lo  = (short*)(w + 2 * MB);
    short* Bt2hi = (short*)(w + 4 * MB);          // E*E shorts = 2MB
    short* Bt2lo = (short*)(w + 6 * MB);
    short* cfTn  = (short*)(w + 0 * MB);          // D*S shorts = 2MB
    short* A4    = (short*)(w + 2 * MB);          // B*S shorts = 1MB
    // [8,12MB): phase A = A1 hi/lo; phase B = Z2
    short* A1hi  = (short*)(w + 8 * MB);          // S*D shorts = 2MB
    short* A1lo  = (short*)(w + 10 * MB);
    float* Z2    = (float*)(w + 8 * MB);          // B*E floats = 4MB
    // [12,14MB): Z1, then a_s
    float* Z1    = (float*)(w + 12 * MB);         // S*E floats = 2MB
    float* a_s   = (float*)(w + 12 * MB);         // B*S floats = 2MB
    // [14,16MB): W_s hi/lo
    short* Wshi  = (short*)(w + 14 * MB);         // S*E shorts = 1MB
    short* Wslo  = (short*)(w + 15 * MB);
    // [16,20MB): Wv3 hi/lo
    short* Wv3hi = (short*)(w + 16 * MB);         // B*E shorts = 2MB
    short* Wv3lo = (short*)(w + 18 * MB);
    // [20MB,...): BN sums + invn
    float* sums1 = (float*)(w + 20 * MB);         // 2*E
    float* sums2 = sums1 + 2 * E_;                // 2*E
    float* invn  = sums2 + 2 * E_;                // S

    hipMemsetAsync(sums1, 0, 4 * E_ * sizeof(float), stream);

    // --- branch 1: Z1 = cf @ fc1_w ; W_s = bn_tanh(Z1) (bias cancels in BN) ---
    split_cvt<<<(S_ * D_) / 1024, 256, 0, stream>>>(cf, A1hi, A1lo, S_ * D_);
    split_cvt_T<<<dim3(E_ / 32, D_ / 32), 256, 0, stream>>>(fc1_w, Bt1hi, Bt1lo, D_, E_);
    row_invnorm<<<S_, 256, 0, stream>>>(cf, invn, D_);
    gemm_mfma_nt<true><<<dim3(E_ / 64, S_ / 64), 256, 0, stream>>>(A1hi, A1lo, Bt1hi, Bt1lo, Z1, S_, E_, D_);
    bn_partial<<<dim3(E_ / 256, 16), 256, 0, stream>>>(Z1, S_ / 16, sums1, E_);
    bn_apply_split<<<(S_ * E_) / 256, 256, 0, stream>>>(Z1, sums1, bn1_g, bn1_b, nullptr, Wshi, Wslo, S_, E_);

    // --- branch 2: Z2 = emb @ fc2_w ; Wv3 = bn_tanh(Z2) * fc3_w ---
    split_cvt<<<(B_ * E_) / 1024, 256, 0, stream>>>(emb, A2hi, A2lo, B_ * E_);
    split_cvt_T<<<dim3(E_ / 32, E_ / 32), 256, 0, stream>>>(fc2_w, Bt2hi, Bt2lo, E_, E_);
    gemm_mfma_nt<true><<<dim3(E_ / 64, B_ / 64), 256, 0, stream>>>(A2hi, A2lo, Bt2hi, Bt2lo, Z2, B_, E_, E_);
    bn_partial<<<dim3(E_ / 256, 16), 256, 0, stream>>>(Z2, B_ / 16, sums2, E_);
    bn_apply_split<<<(B_ * E_) / 256, 256, 0, stream>>>(Z2, sums2, bn2_g, bn2_b, fc3_w, Wv3hi, Wv3lo, B_, E_);

    // --- a_s = Wv3 @ W_s^T (fc3_b cancels in softmax) ---
    gemm_mfma_nt<true><<<dim3(S_ / 64, B_ / 64), 256, 0, stream>>>(Wv3hi, Wv3lo, Wshi, Wslo, a_s, B_, S_, E_);

    // --- weights_v = softmax(a_s * SMOOTH) ---
    softmax_rows<<<B_, 256, 0, stream>>>(a_s, weights_v, A4, S_);

    // --- emb_concept = l2norm( weights_v @ l2norm(cf) ) ---
    cvt_T_scale<<<dim3(D_ / 32, S_ / 32), 256, 0, stream>>>(cf, invn, cfTn, S_, D_);
    gemm_mfma_nt<false><<<dim3(D_ / 64, B_ / 64), 256, 0, stream>>>(A4, nullptr, cfTn, nullptr, emb_concept, B_, D_, S_);
    rownorm_out<<<B_, 256, 0, stream>>>(emb_concept, emb_concept, D_);
}

// Round 3
// 151.769 us; speedup vs baseline: 3.3321x; 1.4660x over previous
//
#include <hip/hip_runtime.h>
#include <hip/hip_bf16.h>
#include <math.h>

#define B_ 1024
#define S_ 512
#define E_ 1024
#define D_ 2048
#define SMOOTH 10.0f

typedef __attribute__((ext_vector_type(8))) short bf16x8;
typedef __attribute__((ext_vector_type(4))) float f32x4;

__device__ __forceinline__ short f2bf(float f) {
    __hip_bfloat16 h = __float2bfloat16(f);
    short s; __builtin_memcpy(&s, &h, 2); return s;
}
__device__ __forceinline__ float bf2f(short s) {
    __hip_bfloat16 h; __builtin_memcpy(&h, &s, 2);
    return __bfloat162float(h);
}

__device__ __forceinline__ void gload16(const short* g, short* l) {
    __builtin_amdgcn_global_load_lds(
        (const __attribute__((address_space(1))) void*)(g),
        (__attribute__((address_space(3))) void*)(l), 16, 0, 0);
}

// ---------------- reduction helpers ----------------
__inline__ __device__ float waveReduceMax(float v) {
#pragma unroll
    for (int o = 32; o; o >>= 1) v = fmaxf(v, __shfl_xor(v, o));
    return v;
}
__inline__ __device__ float waveReduceSum(float v) {
#pragma unroll
    for (int o = 32; o; o >>= 1) v += __shfl_xor(v, o);
    return v;
}

// ---------------- split conversion: x -> hi + lo (bf16 pair) ----------------
__global__ __launch_bounds__(256) void split_cvt(const float* __restrict__ x,
                                                 short* __restrict__ hi,
                                                 short* __restrict__ lo, int n4) {
    int i = (blockIdx.x * 256 + threadIdx.x) * 4;
#pragma unroll
    for (int j = 0; j < 4; j++) {
        float v = x[i + j];
        short h = f2bf(v);
        hi[i + j] = h;
        lo[i + j] = f2bf(v - bf2f(h));
    }
}

// ---------------- transpose + split: out[c][r] = in[r][c] ----------------
__global__ __launch_bounds__(256) void split_cvt_T(const float* __restrict__ in,
                                                   short* __restrict__ hi,
                                                   short* __restrict__ lo,
                                                   int R, int C) {
    __shared__ float t[32][33];
    int c0 = blockIdx.x * 32, r0 = blockIdx.y * 32;
    int cx = threadIdx.x & 31, ry0 = threadIdx.x >> 5;
#pragma unroll
    for (int i = 0; i < 4; i++) {
        int ry = ry0 + i * 8;
        t[ry][cx] = in[(size_t)(r0 + ry) * C + c0 + cx];
    }
    __syncthreads();
    int rx = threadIdx.x & 31, cy0 = threadIdx.x >> 5;
#pragma unroll
    for (int i = 0; i < 4; i++) {
        int cy = cy0 + i * 8;
        float v = t[rx][cy];
        size_t o = (size_t)(c0 + cy) * R + r0 + rx;
        short h = f2bf(v);
        hi[o] = h;
        lo[o] = f2bf(v - bf2f(h));
    }
}

// ---------------- transpose + scale rows + single bf16 ----------------
__global__ __launch_bounds__(256) void cvt_T_scale(const float* __restrict__ in,
                                                   const float* __restrict__ rowscale,
                                                   short* __restrict__ out,
                                                   int R, int C) {
    __shared__ float t[32][33];
    int c0 = blockIdx.x * 32, r0 = blockIdx.y * 32;
    int cx = threadIdx.x & 31, ry0 = threadIdx.x >> 5;
#pragma unroll
    for (int i = 0; i < 4; i++) {
        int ry = ry0 + i * 8;
        t[ry][cx] = in[(size_t)(r0 + ry) * C + c0 + cx] * rowscale[r0 + ry];
    }
    __syncthreads();
    int rx = threadIdx.x & 31, cy0 = threadIdx.x >> 5;
#pragma unroll
    for (int i = 0; i < 4; i++) {
        int cy = cy0 + i * 8;
        out[(size_t)(c0 + cy) * R + r0 + rx] = f2bf(t[rx][cy]);
    }
}

// ---------------- MFMA GEMM, nt form, LDS double-buffered, split-K ----------------
// C_partial(z) = A(MxK)[kz:kz+Kc] @ B(NxK)[kz:kz+Kc]^T for z = blockIdx.z
// 64x64 tile, BK=64, 4 waves (2x2), wave = 32x32 (2x2 frags of 16x16x32).
// LDS tiles XOR-swizzled (chunk ^= row&7) on both stage-source and ds_read.
template<bool SPLIT>
__global__ __launch_bounds__(256) void gemm_lds_nt(const short* __restrict__ Ahi,
                                                   const short* __restrict__ Alo,
                                                   const short* __restrict__ Bhi,
                                                   const short* __restrict__ Blo,
                                                   float* __restrict__ out,
                                                   int M, int N, int K, int Kc) {
    constexpr int NM = SPLIT ? 4 : 2;        // tiles per buffer: Ahi,Bhi[,Alo,Blo]
    __shared__ short lds[2 * NM * 4096];     // 64KB (split) / 32KB
    const int tid = threadIdx.x;
    const int bm = blockIdx.y * 64, bn = blockIdx.x * 64;
    const size_t kz = (size_t)blockIdx.z * Kc;
    float* C = out + (size_t)blockIdx.z * M * N;

    // staging geometry: thread t -> tile row sr (call0) / sr+32 (call1), 16B chunk sc
    const int sr = tid >> 3;
    const int sc = tid & 7;
    const int c8a = sc ^ (sr & 7);            // pre-swizzled source chunk, rows 0..31
    const int c8b = sc ^ ((sr + 32) & 7);     // rows 32..63

    const short* gA = Ahi + (size_t)bm * K + kz;
    const short* gB = Bhi + (size_t)bn * K + kz;
    const short* gAl = SPLIT ? (Alo + (size_t)bm * K + kz) : nullptr;
    const short* gBl = SPLIT ? (Blo + (size_t)bn * K + kz) : nullptr;

    auto stage = [&](int buf, int kt) {
        short* base = lds + buf * (NM * 4096);
        const size_t o1 = (size_t)sr * K + kt + c8a * 8;
        const size_t o2 = (size_t)(sr + 32) * K + kt + c8b * 8;
        gload16(gA + o1, base + tid * 8);
        gload16(gA + o2, base + 2048 + tid * 8);
        gload16(gB + o1, base + 4096 + tid * 8);
        gload16(gB + o2, base + 6144 + tid * 8);
        if (SPLIT) {
            gload16(gAl + o1, base + 8192 + tid * 8);
            gload16(gAl + o2, base + 10240 + tid * 8);
            gload16(gBl + o1, base + 12288 + tid * 8);
            gload16(gBl + o2, base + 14336 + tid * 8);
        }
    };

    const int lane = tid & 63, wid = tid >> 6;
    const int wr = wid >> 1, wc = wid & 1;
    const int r16 = lane & 15, kg = lane >> 4;

    f32x4 acc[2][2] = {};
    const int nt = Kc >> 6;

    stage(0, 0);
    for (int t = 0; t < nt; ++t) {
        __syncthreads();                       // drains tile-t loads (vmcnt) + prior reads
        if (t + 1 < nt) stage((t + 1) & 1, (t + 1) << 6);
        const short* base = lds + (t & 1) * (NM * 4096);
        const short* LA = base;
        const short* LB = base + 4096;
        const short* LAl = base + 8192;
        const short* LBl = base + 12288;
#pragma unroll
        for (int ks = 0; ks < 2; ++ks) {
            bf16x8 ah[2], bh[2];
#pragma unroll
            for (int m = 0; m < 2; m++) {
                int R = wr * 32 + m * 16 + r16;
                ah[m] = *(const bf16x8*)(LA + R * 64 + (((kg + ks * 4) ^ (R & 7)) << 3));
            }
#pragma unroll
            for (int n = 0; n < 2; n++) {
                int R = wc * 32 + n * 16 + r16;
                bh[n] = *(const bf16x8*)(LB + R * 64 + (((kg + ks * 4) ^ (R & 7)) << 3));
            }
#pragma unroll
            for (int m = 0; m < 2; m++)
#pragma unroll
                for (int n = 0; n < 2; n++)
                    acc[m][n] = __builtin_amdgcn_mfma_f32_16x16x32_bf16(ah[m], bh[n], acc[m][n], 0, 0, 0);
            if (SPLIT) {
                bf16x8 al[2], bl[2];
#pragma unroll
                for (int m = 0; m < 2; m++) {
                    int R = wr * 32 + m * 16 + r16;
                    al[m] = *(const bf16x8*)(LAl + R * 64 + (((kg + ks * 4) ^ (R & 7)) << 3));
                }
#pragma unroll
                for (int n = 0; n < 2; n++) {
                    int R = wc * 32 + n * 16 + r16;
                    bl[n] = *(const bf16x8*)(LBl + R * 64 + (((kg + ks * 4) ^ (R & 7)) << 3));
                }
#pragma unroll
                for (int m = 0; m < 2; m++)
#pragma unroll
                    for (int n = 0; n < 2; n++) {
                        acc[m][n] = __builtin_amdgcn_mfma_f32_16x16x32_bf16(ah[m], bl[n], acc[m][n], 0, 0, 0);
                        acc[m][n] = __builtin_amdgcn_mfma_f32_16x16x32_bf16(al[m], bh[n], acc[m][n], 0, 0, 0);
                    }
            }
        }
    }

#pragma unroll
    for (int m = 0; m < 2; m++)
#pragma unroll
        for (int n = 0; n < 2; n++) {
            int col = bn + wc * 32 + n * 16 + r16;
#pragma unroll
            for (int r = 0; r < 4; r++) {
                int row = bm + wr * 32 + m * 16 + kg * 4 + r;
                C[(size_t)row * N + col] = acc[m][n][r];
            }
        }
}

// ---------------- split-K reduce + BN partial sums ----------------
__global__ __launch_bounds__(256) void bn_partial_reduce(const float* __restrict__ P,
                                                         int KS, int rows_per,
                                                         float* __restrict__ Z,
                                                         float* __restrict__ sums,
                                                         int E, int M) {
    int c = blockIdx.x * 256 + threadIdx.x;
    int r0 = blockIdx.y * rows_per;
    size_t slice = (size_t)M * E;
    float s = 0.f, ss = 0.f;
    for (int r = r0; r < r0 + rows_per; r++) {
        float z = 0.f;
        for (int k = 0; k < KS; k++) z += P[k * slice + (size_t)r * E + c];
        Z[(size_t)r * E + c] = z;
        s += z;
        ss += z * z;
    }
    atomicAdd(&sums[c], s);
    atomicAdd(&sums[E + c], ss);
}

// ---------------- BN finalize + tanh (+ scale) -> bf16 hi/lo ----------------
__global__ __launch_bounds__(256) void bn_apply_split(const float* __restrict__ Z,
                                                      const float* __restrict__ sums,
                                                      const float* __restrict__ g,
                                                      const float* __restrict__ b,
                                                      const float* __restrict__ scale,
                                                      short* __restrict__ Whi,
                                                      short* __restrict__ Wlo,
                                                      int R, int E) {
    int idx = blockIdx.x * 256 + threadIdx.x;
    int c = idx & (E - 1);
    float invR = 1.0f / (float)R;
    float mu = sums[c] * invR;
    float var = sums[E + c] * invR - mu * mu;
    float rstd = rsqrtf(var + 1e-5f);
    float w = tanhf(g[c] * (Z[idx] - mu) * rstd + b[c]);
    if (scale) w *= scale[c];
    short h = f2bf(w);
    Whi[idx] = h;
    Wlo[idx] = f2bf(w - bf2f(h));
}

// ---------------- split-K reduce + row softmax (n=512), fp32 + bf16 out ----------------
__global__ __launch_bounds__(256) void softmax_fused(const float* __restrict__ P, int KS,
                                                     float* __restrict__ O,
                                                     short* __restrict__ O16, int n, int M) {
    __shared__ float red[4];
    int row = blockIdx.x;
    size_t slice = (size_t)M * n;
    int t = threadIdx.x;
    float v0 = 0.f, v1 = 0.f;
    for (int k = 0; k < KS; k++) {
        v0 += P[k * slice + (size_t)row * n + t];
        v1 += P[k * slice + (size_t)row * n + t + 256];
    }
    v0 *= SMOOTH;
    v1 *= SMOOTH;
    float m = waveReduceMax(fmaxf(v0, v1));
    if ((t & 63) == 0) red[t >> 6] = m;
    __syncthreads();
    m = fmaxf(fmaxf(red[0], red[1]), fmaxf(red[2], red[3]));
    float e0 = __expf(v0 - m), e1 = __expf(v1 - m);
    float s = waveReduceSum(e0 + e1);
    __syncthreads();
    if ((t & 63) == 0) red[t >> 6] = s;
    __syncthreads();
    s = red[0] + red[1] + red[2] + red[3];
    float inv = 1.0f / s;
    float w0 = e0 * inv, w1 = e1 * inv;
    O[(size_t)row * n + t] = w0;
    O[(size_t)row * n + t + 256] = w1;
    O16[(size_t)row * n + t] = f2bf(w0);
    O16[(size_t)row * n + t + 256] = f2bf(w1);
}

// ---------------- per-row inverse norm ----------------
__global__ __launch_bounds__(256) void row_invnorm(const float* __restrict__ X,
                                                   float* __restrict__ inv, int n) {
    __shared__ float red[4];
    int row = blockIdx.x;
    const float* x = X + (size_t)row * n;
    float ss = 0.f;
    for (int i = threadIdx.x; i < n; i += 256) {
        float v = x[i];
        ss += v * v;
    }
    ss = waveReduceSum(ss);
    if ((threadIdx.x & 63) == 0) red[threadIdx.x >> 6] = ss;
    __syncthreads();
    ss = red[0] + red[1] + red[2] + red[3];
    if (threadIdx.x == 0) inv[row] = 1.0f / (sqrtf(ss) + 1e-8f);
}

// ---------------- row l2norm (in-place safe) ----------------
__global__ __launch_bounds__(256) void rownorm_out(const float* __restrict__ X,
                                                   float* __restrict__ O, int n) {
    __shared__ float red[4];
    int row = blockIdx.x;
    const float* x = X + (size_t)row * n;
    float ss = 0.f;
    for (int i = threadIdx.x; i < n; i += 256) {
        float v = x[i];
        ss += v * v;
    }
    ss = waveReduceSum(ss);
    if ((threadIdx.x & 63) == 0) red[threadIdx.x >> 6] = ss;
    __syncthreads();
    ss = red[0] + red[1] + red[2] + red[3];
    float s = 1.0f / (sqrtf(ss) + 1e-8f);
    for (int i = threadIdx.x; i < n; i += 256)
        O[(size_t)row * n + i] = x[i] * s;
}

extern "C" void kernel_launch(void* const* d_in, const int* in_sizes, int n_in,
                              void* d_out, int out_size, void* d_ws, size_t ws_size,
                              hipStream_t stream) {
    const float* emb   = (const float*)d_in[0];   // (B,E)
    const float* cf    = (const float*)d_in[1];   // (S,D)
    const float* fc1_w = (const float*)d_in[3];   // (D,E)
    const float* bn1_g = (const float*)d_in[5];
    const float* bn1_b = (const float*)d_in[6];
    const float* fc2_w = (const float*)d_in[7];   // (E,E)
    const float* bn2_g = (const float*)d_in[9];
    const float* bn2_b = (const float*)d_in[10];
    const float* fc3_w = (const float*)d_in[11];  // (E,)

    float* out = (float*)d_out;
    float* emb_concept = out;                     // B*D (8MB) — doubles as split-K partial buffer
    float* weights_v   = out + (size_t)B_ * D_;   // B*S
    float* P           = emb_concept;             // split-K partials (<= 8MB), dead until GEMM4

    const size_t MB = 1024 * 1024;
    char* w = (char*)d_ws;
    // [0,8MB): phase A = Bt1 hi/lo; phase B = A2 hi/lo + Bt2 hi/lo; phase C = cfTn + A4
    short* Bt1hi = (short*)(w + 0 * MB);          // E*D shorts = 4MB
    short* Bt1lo = (short*)(w + 4 * MB);
    short* A2hi  = (short*)(w + 0 * MB);          // B*E shorts = 2MB
    short* A2lo  = (short*)(w + 2 * MB);
    short* Bt2hi = (short*)(w + 4 * MB);          // E*E shorts = 2MB
    short* Bt2lo = (short*)(w + 6 * MB);
    short* cfTn  = (short*)(w + 0 * MB);          // D*S shorts = 2MB
    short* A4    = (short*)(w + 2 * MB);          // B*S shorts = 1MB
    // [8,12MB): phase A = A1 hi/lo; phase B = Z2
    short* A1hi  = (short*)(w + 8 * MB);          // S*D shorts = 2MB
    short* A1lo  = (short*)(w + 10 * MB);
    float* Z2    = (float*)(w + 8 * MB);          // B*E floats = 4MB
    // [12,14MB): Z1
    float* Z1    = (float*)(w + 12 * MB);         // S*E floats = 2MB
    // [14,16MB): W_s hi/lo
    short* Wshi  = (short*)(w + 14 * MB);         // S*E shorts = 1MB
    short* Wslo  = (short*)(w + 15 * MB);
    // [16,20MB): Wv3 hi/lo
    short* Wv3hi = (short*)(w + 16 * MB);         // B*E shorts = 2MB
    short* Wv3lo = (short*)(w + 18 * MB);
    // [20MB,...): BN sums + invn
    float* sums1 = (float*)(w + 20 * MB);         // 2*E
    float* sums2 = sums1 + 2 * E_;                // 2*E
    float* invn  = sums2 + 2 * E_;                // S

    hipMemsetAsync(sums1, 0, 4 * E_ * sizeof(float), stream);

    // --- branch 1: Z1 = cf @ fc1_w ; W_s = bn_tanh(Z1) (bias cancels in BN) ---
    split_cvt<<<(S_ * D_) / 1024, 256, 0, stream>>>(cf, A1hi, A1lo, S_ * D_);
    split_cvt_T<<<dim3(E_ / 32, D_ / 32), 256, 0, stream>>>(fc1_w, Bt1hi, Bt1lo, D_, E_);
    row_invnorm<<<S_, 256, 0, stream>>>(cf, invn, D_);
    gemm_lds_nt<true><<<dim3(E_ / 64, S_ / 64, 4), 256, 0, stream>>>(A1hi, A1lo, Bt1hi, Bt1lo, P, S_, E_, D_, D_ / 4);
    bn_partial_reduce<<<dim3(E_ / 256, 16), 256, 0, stream>>>(P, 4, S_ / 16, Z1, sums1, E_, S_);
    bn_apply_split<<<(S_ * E_) / 256, 256, 0, stream>>>(Z1, sums1, bn1_g, bn1_b, nullptr, Wshi, Wslo, S_, E_);

    // --- branch 2: Z2 = emb @ fc2_w ; Wv3 = bn_tanh(Z2) * fc3_w ---
    split_cvt<<<(B_ * E_) / 1024, 256, 0, stream>>>(emb, A2hi, A2lo, B_ * E_);
    split_cvt_T<<<dim3(E_ / 32, E_ / 32), 256, 0, stream>>>(fc2_w, Bt2hi, Bt2lo, E_, E_);
    gemm_lds_nt<true><<<dim3(E_ / 64, B_ / 64, 2), 256, 0, stream>>>(A2hi, A2lo, Bt2hi, Bt2lo, P, B_, E_, E_, E_ / 2);
    bn_partial_reduce<<<dim3(E_ / 256, 16), 256, 0, stream>>>(P, 2, B_ / 16, Z2, sums2, E_, B_);
    bn_apply_split<<<(B_ * E_) / 256, 256, 0, stream>>>(Z2, sums2, bn2_g, bn2_b, fc3_w, Wv3hi, Wv3lo, B_, E_);

    // --- a_s = Wv3 @ W_s^T (fc3_b cancels in softmax), reduced inside softmax ---
    gemm_lds_nt<true><<<dim3(S_ / 64, B_ / 64, 4), 256, 0, stream>>>(Wv3hi, Wv3lo, Wshi, Wslo, P, B_, S_, E_, E_ / 4);

    // --- weights_v = softmax(sum_k P_k * SMOOTH) ---
    softmax_fused<<<B_, 256, 0, stream>>>(P, 4, weights_v, A4, S_, B_);

    // --- emb_concept = l2norm( weights_v @ l2norm(cf) ) ---
    cvt_T_scale<<<dim3(D_ / 32, S_ / 32), 256, 0, stream>>>(cf, invn, cfTn, S_, D_);
    gemm_lds_nt<false><<<dim3(D_ / 64, B_ / 64, 1), 256, 0, stream>>>(A4, nullptr, cfTn, nullptr, emb_concept, B_, D_, S_, S_);
    rownorm_out<<<B_, 256, 0, stream>>>(emb_concept, emb_concept, D_);
}

// Round 4
// 127.650 us; speedup vs baseline: 3.9617x; 1.1890x over previous
//
#include <hip/hip_runtime.h>
#include <hip/hip_bf16.h>
#include <math.h>

#define B_ 1024
#define S_ 512
#define E_ 1024
#define D_ 2048
#define SMOOTH 10.0f

typedef __attribute__((ext_vector_type(8))) short bf16x8;
typedef __attribute__((ext_vector_type(4))) float f32x4;

__device__ __forceinline__ short f2bf(float f) {
    __hip_bfloat16 h = __float2bfloat16(f);
    short s; __builtin_memcpy(&s, &h, 2); return s;
}
__device__ __forceinline__ float bf2f(short s) {
    __hip_bfloat16 h; __builtin_memcpy(&h, &s, 2);
    return __bfloat162float(h);
}

__device__ __forceinline__ void gload16(const short* g, short* l) {
    __builtin_amdgcn_global_load_lds(
        (const __attribute__((address_space(1))) void*)(g),
        (__attribute__((address_space(3))) void*)(l), 16, 0, 0);
}

// ---------------- reduction helpers ----------------
__inline__ __device__ float waveReduceMax(float v) {
#pragma unroll
    for (int o = 32; o; o >>= 1) v = fmaxf(v, __shfl_xor(v, o));
    return v;
}
__inline__ __device__ float waveReduceSum(float v) {
#pragma unroll
    for (int o = 32; o; o >>= 1) v += __shfl_xor(v, o);
    return v;
}

// ---------------- transpose helpers (32x32 tile via LDS) ----------------
__device__ __forceinline__ void transpose_split(const float* __restrict__ in,
                                                short* __restrict__ hi,
                                                short* __restrict__ lo,
                                                int R, int C, int r0, int c0,
                                                int tid, float (*t)[33]) {
    int cx = tid & 31, ry0 = tid >> 5;
#pragma unroll
    for (int i = 0; i < 4; i++) {
        int ry = ry0 + i * 8;
        t[ry][cx] = in[(size_t)(r0 + ry) * C + c0 + cx];
    }
    __syncthreads();
    int rx = tid & 31, cy0 = tid >> 5;
#pragma unroll
    for (int i = 0; i < 4; i++) {
        int cy = cy0 + i * 8;
        float v = t[rx][cy];
        size_t o = (size_t)(c0 + cy) * R + r0 + rx;
        short h = f2bf(v);
        hi[o] = h;
        if (lo) lo[o] = f2bf(v - bf2f(h));
    }
}

// ---------------- fused preprocessing: one kernel, blockIdx-segmented ----------------
// seg0 [0,512):        cf row -> A1hi/lo + invn (row l2 inverse norm)
// seg1 [512,1024):     emb elementwise -> A2hi/lo
// seg2 [1024,3072):    fc1_w (DxE) -> Bt1 (ExD) split transpose
// seg3 [3072,4096):    fc2_w (ExE) -> Bt2 (ExE) split transpose
// seg4 [4096,5120):    cf (SxD) -> cfT (DxS) single-bf16 transpose
__global__ __launch_bounds__(256) void prep(const float* __restrict__ cf,
                                            const float* __restrict__ emb,
                                            const float* __restrict__ fc1_w,
                                            const float* __restrict__ fc2_w,
                                            short* __restrict__ A1hi, short* __restrict__ A1lo,
                                            float* __restrict__ invn,
                                            short* __restrict__ A2hi, short* __restrict__ A2lo,
                                            short* __restrict__ Bt1hi, short* __restrict__ Bt1lo,
                                            short* __restrict__ Bt2hi, short* __restrict__ Bt2lo,
                                            short* __restrict__ cfT) {
    __shared__ float t[32][33];
    __shared__ float red[4];
    const int bid = blockIdx.x;
    const int tid = threadIdx.x;
    if (bid < 512) {
        int row = bid;
        const float* x = cf + (size_t)row * D_;
        float ss = 0.f;
#pragma unroll
        for (int j = 0; j < 8; j++) {
            int i = j * 256 + tid;
            float v = x[i];
            short h = f2bf(v);
            A1hi[(size_t)row * D_ + i] = h;
            A1lo[(size_t)row * D_ + i] = f2bf(v - bf2f(h));
            ss += v * v;
        }
        ss = waveReduceSum(ss);
        if ((tid & 63) == 0) red[tid >> 6] = ss;
        __syncthreads();
        if (tid == 0) {
            float s = red[0] + red[1] + red[2] + red[3];
            invn[row] = 1.0f / (sqrtf(s) + 1e-8f);
        }
    } else if (bid < 1024) {
        size_t base = (size_t)(bid - 512) * 2048;
#pragma unroll
        for (int j = 0; j < 8; j++) {
            size_t i = base + j * 256 + tid;
            float v = emb[i];
            short h = f2bf(v);
            A2hi[i] = h;
            A2lo[i] = f2bf(v - bf2f(h));
        }
    } else if (bid < 3072) {
        int b2 = bid - 1024;
        int c0 = (b2 & 31) * 32;   // over C=E (32 tiles)
        int r0 = (b2 >> 5) * 32;   // over R=D (64 tiles)
        transpose_split(fc1_w, Bt1hi, Bt1lo, D_, E_, r0, c0, tid, t);
    } else if (bid < 4096) {
        int b2 = bid - 3072;
        int c0 = (b2 & 31) * 32;   // over C=E
        int r0 = (b2 >> 5) * 32;   // over R=E
        transpose_split(fc2_w, Bt2hi, Bt2lo, E_, E_, r0, c0, tid, t);
    } else {
        int b2 = bid - 4096;
        int c0 = (b2 & 63) * 32;   // over C=D (64 tiles)
        int r0 = (b2 >> 6) * 32;   // over R=S (16 tiles)
        transpose_split(cf, cfT, nullptr, S_, D_, r0, c0, tid, t);
    }
}

// ---------------- MFMA GEMM, nt form, LDS double-buffered, split-K ----------------
// C_partial(z) = A(MxK)[kz:kz+Kc] @ B(NxK)[kz:kz+Kc]^T for z = blockIdx.z
// 64x64 tile, BK=64, 4 waves (2x2), wave = 32x32 (2x2 frags of 16x16x32).
// LDS tiles XOR-swizzled (chunk ^= row&7) on both stage-source and ds_read.
template<bool SPLIT>
__global__ __launch_bounds__(256) void gemm_lds_nt(const short* __restrict__ Ahi,
                                                   const short* __restrict__ Alo,
                                                   const short* __restrict__ Bhi,
                                                   const short* __restrict__ Blo,
                                                   float* __restrict__ out,
                                                   int M, int N, int K, int Kc) {
    constexpr int NM = SPLIT ? 4 : 2;
    __shared__ short lds[2 * NM * 4096];
    const int tid = threadIdx.x;
    const int bm = blockIdx.y * 64, bn = blockIdx.x * 64;
    const size_t kz = (size_t)blockIdx.z * Kc;
    float* C = out + (size_t)blockIdx.z * M * N;

    const int sr = tid >> 3;
    const int sc = tid & 7;
    const int c8a = sc ^ (sr & 7);
    const int c8b = sc ^ ((sr + 32) & 7);

    const short* gA = Ahi + (size_t)bm * K + kz;
    const short* gB = Bhi + (size_t)bn * K + kz;
    const short* gAl = SPLIT ? (Alo + (size_t)bm * K + kz) : nullptr;
    const short* gBl = SPLIT ? (Blo + (size_t)bn * K + kz) : nullptr;

    auto stage = [&](int buf, int kt) {
        short* base = lds + buf * (NM * 4096);
        const size_t o1 = (size_t)sr * K + kt + c8a * 8;
        const size_t o2 = (size_t)(sr + 32) * K + kt + c8b * 8;
        gload16(gA + o1, base + tid * 8);
        gload16(gA + o2, base + 2048 + tid * 8);
        gload16(gB + o1, base + 4096 + tid * 8);
        gload16(gB + o2, base + 6144 + tid * 8);
        if (SPLIT) {
            gload16(gAl + o1, base + 8192 + tid * 8);
            gload16(gAl + o2, base + 10240 + tid * 8);
            gload16(gBl + o1, base + 12288 + tid * 8);
            gload16(gBl + o2, base + 14336 + tid * 8);
        }
    };

    const int lane = tid & 63, wid = tid >> 6;
    const int wr = wid >> 1, wc = wid & 1;
    const int r16 = lane & 15, kg = lane >> 4;

    f32x4 acc[2][2] = {};
    const int nt = Kc >> 6;

    stage(0, 0);
    for (int t = 0; t < nt; ++t) {
        __syncthreads();
        if (t + 1 < nt) stage((t + 1) & 1, (t + 1) << 6);
        const short* base = lds + (t & 1) * (NM * 4096);
        const short* LA = base;
        const short* LB = base + 4096;
        const short* LAl = base + 8192;
        const short* LBl = base + 12288;
#pragma unroll
        for (int ks = 0; ks < 2; ++ks) {
            bf16x8 ah[2], bh[2];
#pragma unroll
            for (int m = 0; m < 2; m++) {
                int R = wr * 32 + m * 16 + r16;
                ah[m] = *(const bf16x8*)(LA + R * 64 + (((kg + ks * 4) ^ (R & 7)) << 3));
            }
#pragma unroll
            for (int n = 0; n < 2; n++) {
                int R = wc * 32 + n * 16 + r16;
                bh[n] = *(const bf16x8*)(LB + R * 64 + (((kg + ks * 4) ^ (R & 7)) << 3));
            }
#pragma unroll
            for (int m = 0; m < 2; m++)
#pragma unroll
                for (int n = 0; n < 2; n++)
                    acc[m][n] = __builtin_amdgcn_mfma_f32_16x16x32_bf16(ah[m], bh[n], acc[m][n], 0, 0, 0);
            if (SPLIT) {
                bf16x8 al[2], bl[2];
#pragma unroll
                for (int m = 0; m < 2; m++) {
                    int R = wr * 32 + m * 16 + r16;
                    al[m] = *(const bf16x8*)(LAl + R * 64 + (((kg + ks * 4) ^ (R & 7)) << 3));
                }
#pragma unroll
                for (int n = 0; n < 2; n++) {
                    int R = wc * 32 + n * 16 + r16;
                    bl[n] = *(const bf16x8*)(LBl + R * 64 + (((kg + ks * 4) ^ (R & 7)) << 3));
                }
#pragma unroll
                for (int m = 0; m < 2; m++)
#pragma unroll
                    for (int n = 0; n < 2; n++) {
                        acc[m][n] = __builtin_amdgcn_mfma_f32_16x16x32_bf16(ah[m], bl[n], acc[m][n], 0, 0, 0);
                        acc[m][n] = __builtin_amdgcn_mfma_f32_16x16x32_bf16(al[m], bh[n], acc[m][n], 0, 0, 0);
                    }
            }
        }
    }

#pragma unroll
    for (int m = 0; m < 2; m++)
#pragma unroll
        for (int n = 0; n < 2; n++) {
            int col = bn + wc * 32 + n * 16 + r16;
#pragma unroll
            for (int r = 0; r < 4; r++) {
                int row = bm + wr * 32 + m * 16 + kg * 4 + r;
                C[(size_t)row * N + col] = acc[m][n][r];
            }
        }
}

// ---------------- split-K reduce + per-slice BN partial sums (no atomics) ----------------
__global__ __launch_bounds__(256) void bn_stats(const float* __restrict__ P, int KS,
                                                int rows_per, float* __restrict__ Z,
                                                float* __restrict__ part, int E, int M) {
    int c = blockIdx.x * 256 + threadIdx.x;
    int r0 = blockIdx.y * rows_per;
    size_t slice = (size_t)M * E;
    float s = 0.f, ss = 0.f;
    for (int r = r0; r < r0 + rows_per; r++) {
        float z = 0.f;
        for (int k = 0; k < KS; k++) z += P[k * slice + (size_t)r * E + c];
        Z[(size_t)r * E + c] = z;
        s += z;
        ss += z * z;
    }
    part[(size_t)blockIdx.y * 2 * E + c] = s;
    part[(size_t)blockIdx.y * 2 * E + E + c] = ss;
}

// ---------------- BN finalize + tanh (+ scale) -> bf16 hi/lo ----------------
// column-persistent: thread reduces NS partials for its column, then applies rows.
__global__ __launch_bounds__(256) void bn_apply_split(const float* __restrict__ Z,
                                                      const float* __restrict__ part, int NS,
                                                      const float* __restrict__ g,
                                                      const float* __restrict__ b,
                                                      const float* __restrict__ scale,
                                                      short* __restrict__ Whi,
                                                      short* __restrict__ Wlo,
                                                      int R, int E, int rows_per) {
    int c = blockIdx.x * 256 + threadIdx.x;
    float s = 0.f, ss = 0.f;
    for (int k = 0; k < NS; k++) {
        s += part[(size_t)k * 2 * E + c];
        ss += part[(size_t)k * 2 * E + E + c];
    }
    float invR = 1.0f / (float)R;
    float mu = s * invR;
    float var = ss * invR - mu * mu;
    float rstd = rsqrtf(var + 1e-5f);
    float Aa = g[c] * rstd;
    float Bb = b[c] - Aa * mu;
    float sc = scale ? scale[c] : 1.0f;
    int r0 = blockIdx.y * rows_per;
    for (int r = r0; r < r0 + rows_per; r++) {
        size_t idx = (size_t)r * E + c;
        float w = tanhf(fmaf(Z[idx], Aa, Bb)) * sc;
        short h = f2bf(w);
        Whi[idx] = h;
        Wlo[idx] = f2bf(w - bf2f(h));
    }
}

// ---------------- split-K reduce + row softmax (n=512), fp32 out + invn-scaled bf16 ----------------
__global__ __launch_bounds__(256) void softmax_fused(const float* __restrict__ P, int KS,
                                                     const float* __restrict__ invn,
                                                     float* __restrict__ O,
                                                     short* __restrict__ O16, int n, int M) {
    __shared__ float red[4];
    int row = blockIdx.x;
    size_t slice = (size_t)M * n;
    int t = threadIdx.x;
    float v0 = 0.f, v1 = 0.f;
    for (int k = 0; k < KS; k++) {
        v0 += P[k * slice + (size_t)row * n + t];
        v1 += P[k * slice + (size_t)row * n + t + 256];
    }
    v0 *= SMOOTH;
    v1 *= SMOOTH;
    float m = waveReduceMax(fmaxf(v0, v1));
    if ((t & 63) == 0) red[t >> 6] = m;
    __syncthreads();
    m = fmaxf(fmaxf(red[0], red[1]), fmaxf(red[2], red[3]));
    float e0 = __expf(v0 - m), e1 = __expf(v1 - m);
    float s = waveReduceSum(e0 + e1);
    __syncthreads();
    if ((t & 63) == 0) red[t >> 6] = s;
    __syncthreads();
    s = red[0] + red[1] + red[2] + red[3];
    float inv = 1.0f / s;
    float w0 = e0 * inv, w1 = e1 * inv;
    O[(size_t)row * n + t] = w0;
    O[(size_t)row * n + t + 256] = w1;
    // fold l2norm(cf) row scale (contracted index) into the bf16 GEMM-A operand
    O16[(size_t)row * n + t] = f2bf(w0 * invn[t]);
    O16[(size_t)row * n + t + 256] = f2bf(w1 * invn[t + 256]);
}

// ---------------- row l2norm (in-place safe) ----------------
__global__ __launch_bounds__(256) void rownorm_out(const float* __restrict__ X,
                                                   float* __restrict__ O, int n) {
    __shared__ float red[4];
    int row = blockIdx.x;
    const float* x = X + (size_t)row * n;
    float ss = 0.f;
    for (int i = threadIdx.x; i < n; i += 256) {
        float v = x[i];
        ss += v * v;
    }
    ss = waveReduceSum(ss);
    if ((threadIdx.x & 63) == 0) red[threadIdx.x >> 6] = ss;
    __syncthreads();
    ss = red[0] + red[1] + red[2] + red[3];
    float s = 1.0f / (sqrtf(ss) + 1e-8f);
    for (int i = threadIdx.x; i < n; i += 256)
        O[(size_t)row * n + i] = x[i] * s;
}

extern "C" void kernel_launch(void* const* d_in, const int* in_sizes, int n_in,
                              void* d_out, int out_size, void* d_ws, size_t ws_size,
                              hipStream_t stream) {
    const float* emb   = (const float*)d_in[0];   // (B,E)
    const float* cf    = (const float*)d_in[1];   // (S,D)
    const float* fc1_w = (const float*)d_in[3];   // (D,E)
    const float* bn1_g = (const float*)d_in[5];
    const float* bn1_b = (const float*)d_in[6];
    const float* fc2_w = (const float*)d_in[7];   // (E,E)
    const float* bn2_g = (const float*)d_in[9];
    const float* bn2_b = (const float*)d_in[10];
    const float* fc3_w = (const float*)d_in[11];  // (E,)

    float* out = (float*)d_out;
    float* emb_concept = out;                     // B*D (8MB) — doubles as split-K partial buffer
    float* weights_v   = out + (size_t)B_ * D_;   // B*S
    float* P           = emb_concept;             // split-K partials (8MB), dead until GEMM4

    const size_t MB = 1024 * 1024;
    char* w = (char*)d_ws;                        // ws >= 256MB; everything disjoint
    short* Bt1hi = (short*)(w + 0 * MB);          // E*D = 4MB
    short* Bt1lo = (short*)(w + 4 * MB);          // 4MB
    short* Bt2hi = (short*)(w + 8 * MB);          // E*E = 2MB
    short* Bt2lo = (short*)(w + 10 * MB);         // 2MB
    short* A1hi  = (short*)(w + 12 * MB);         // S*D = 2MB
    short* A1lo  = (short*)(w + 14 * MB);         // 2MB
    short* A2hi  = (short*)(w + 16 * MB);         // B*E = 2MB
    short* A2lo  = (short*)(w + 18 * MB);         // 2MB
    short* cfT   = (short*)(w + 20 * MB);         // D*S = 2MB
    float* Z1    = (float*)(w + 22 * MB);         // S*E = 2MB
    float* Z2    = (float*)(w + 24 * MB);         // B*E = 4MB
    short* Wshi  = (short*)(w + 28 * MB);         // 1MB
    short* Wslo  = (short*)(w + 29 * MB);         // 1MB
    short* Wv3hi = (short*)(w + 30 * MB);         // 2MB
    short* Wv3lo = (short*)(w + 32 * MB);         // 2MB
    short* A4    = (short*)(w + 34 * MB);         // B*S = 1MB
    float* part1 = (float*)(w + 35 * MB);         // 32*2*E = 256KB
    float* part2 = (float*)(w + 36 * MB);         // 256KB
    float* invn  = (float*)(w + 37 * MB);         // S

    // --- all conversions/transposes in one kernel ---
    prep<<<5120, 256, 0, stream>>>(cf, emb, fc1_w, fc2_w,
                                   A1hi, A1lo, invn, A2hi, A2lo,
                                   Bt1hi, Bt1lo, Bt2hi, Bt2lo, cfT);

    // --- branch 1: Z1 = cf @ fc1_w ; W_s = bn_tanh(Z1) ---
    gemm_lds_nt<true><<<dim3(16, 8, 4), 256, 0, stream>>>(A1hi, A1lo, Bt1hi, Bt1lo, P, S_, E_, D_, D_ / 4);
    bn_stats<<<dim3(4, 32), 256, 0, stream>>>(P, 4, S_ / 32, Z1, part1, E_, S_);
    bn_apply_split<<<dim3(4, 32), 256, 0, stream>>>(Z1, part1, 32, bn1_g, bn1_b, nullptr, Wshi, Wslo, S_, E_, 16);

    // --- branch 2: Z2 = emb @ fc2_w ; Wv3 = bn_tanh(Z2) * fc3_w ---
    gemm_lds_nt<true><<<dim3(16, 16, 2), 256, 0, stream>>>(A2hi, A2lo, Bt2hi, Bt2lo, P, B_, E_, E_, E_ / 2);
    bn_stats<<<dim3(4, 32), 256, 0, stream>>>(P, 2, B_ / 32, Z2, part2, E_, B_);
    bn_apply_split<<<dim3(4, 64), 256, 0, stream>>>(Z2, part2, 32, bn2_g, bn2_b, fc3_w, Wv3hi, Wv3lo, B_, E_, 16);

    // --- a_s = Wv3 @ W_s^T (fc3_b cancels in softmax), reduced inside softmax ---
    gemm_lds_nt<true><<<dim3(8, 16, 4), 256, 0, stream>>>(Wv3hi, Wv3lo, Wshi, Wslo, P, B_, S_, E_, E_ / 4);

    // --- weights_v = softmax(sum_k P_k * SMOOTH); A4 = bf16(w * invn) ---
    softmax_fused<<<B_, 256, 0, stream>>>(P, 4, invn, weights_v, A4, S_, B_);

    // --- emb_concept = l2norm( (w*invn) @ cf^T^T ) ---
    gemm_lds_nt<false><<<dim3(32, 16, 1), 256, 0, stream>>>(A4, nullptr, cfT, nullptr, emb_concept, B_, D_, S_, S_);
    rownorm_out<<<B_, 256, 0, stream>>>(emb_concept, emb_concept, D_);
}

// Round 5
// 75.782 us; speedup vs baseline: 6.6733x; 1.6844x over previous
//
#include <hip/hip_runtime.h>
#include <hip/hip_bf16.h>
#include <math.h>

#define B_ 1024
#define S_ 512
#define E_ 1024
#define D_ 2048
#define SMOOTH 10.0f

typedef __attribute__((ext_vector_type(8))) short bf16x8;
typedef __attribute__((ext_vector_type(4))) float f32x4;

__device__ __forceinline__ short f2bf(float f) {
    __hip_bfloat16 h = __float2bfloat16(f);
    short s; __builtin_memcpy(&s, &h, 2); return s;
}
__device__ __forceinline__ float bf2f(short s) {
    __hip_bfloat16 h; __builtin_memcpy(&h, &s, 2);
    return __bfloat162float(h);
}

__device__ __forceinline__ void gload16(const short* g, short* l) {
    __builtin_amdgcn_global_load_lds(
        (const __attribute__((address_space(1))) void*)(g),
        (__attribute__((address_space(3))) void*)(l), 16, 0, 0);
}

__inline__ __device__ float waveReduceMax(float v) {
#pragma unroll
    for (int o = 32; o; o >>= 1) v = fmaxf(v, __shfl_xor(v, o));
    return v;
}
__inline__ __device__ float waveReduceSum(float v) {
#pragma unroll
    for (int o = 32; o; o >>= 1) v += __shfl_xor(v, o);
    return v;
}

// ---------------- transpose helper (32x32 tile via LDS) ----------------
// out[(c0+cy)*ldo + r0+rx] = hi(in[(r0+ry)*C + c0+cx]); lo at +loOff (if loOff>0)
__device__ __forceinline__ void transpose_split(const float* __restrict__ in,
                                                short* __restrict__ out,
                                                int C, int r0, int c0,
                                                int ldo, int loOff,
                                                int tid, float (*t)[33]) {
    int cx = tid & 31, ry0 = tid >> 5;
#pragma unroll
    for (int i = 0; i < 4; i++) {
        int ry = ry0 + i * 8;
        t[ry][cx] = in[(size_t)(r0 + ry) * C + c0 + cx];
    }
    __syncthreads();
    int rx = tid & 31, cy0 = tid >> 5;
#pragma unroll
    for (int i = 0; i < 4; i++) {
        int cy = cy0 + i * 8;
        float v = t[rx][cy];
        size_t o = (size_t)(c0 + cy) * ldo + r0 + rx;
        short h = f2bf(v);
        out[o] = h;
        if (loOff > 0) out[o + loOff] = f2bf(v - bf2f(h));
    }
}

// ---------------- fused preprocessing, blockIdx-segmented ----------------
// seg0 [0,512):      cf row -> A1 concat-K (4096 wide) + invn
// seg1 [512,1024):   emb (2 rows/blk) -> A2 concat-K (2048 wide)
// seg2 [1024,3072):  fc1_w (2048x1024) -> Bt1 (1024 x 4096) split-T
// seg3 [3072,4096):  fc2_w (1024x1024) -> Bt2 (1024 x 2048) split-T
// seg4 [4096,5120):  cf (512x2048) -> cfT (2048 x 512) bf16-T
__global__ __launch_bounds__(256) void prep(const float* __restrict__ cf,
                                            const float* __restrict__ emb,
                                            const float* __restrict__ fc1_w,
                                            const float* __restrict__ fc2_w,
                                            short* __restrict__ A1,
                                            float* __restrict__ invn,
                                            short* __restrict__ A2,
                                            short* __restrict__ Bt1,
                                            short* __restrict__ Bt2,
                                            short* __restrict__ cfT) {
    __shared__ float t[32][33];
    __shared__ float red[4];
    const int bid = blockIdx.x;
    const int tid = threadIdx.x;
    if (bid < 512) {
        int row = bid;
        const float* x = cf + (size_t)row * D_;
        short* a = A1 + (size_t)row * (2 * D_);
        float ss = 0.f;
#pragma unroll
        for (int j = 0; j < 8; j++) {
            int i = j * 256 + tid;
            float v = x[i];
            short h = f2bf(v);
            a[i] = h;
            a[D_ + i] = f2bf(v - bf2f(h));
            ss += v * v;
        }
        ss = waveReduceSum(ss);
        if ((tid & 63) == 0) red[tid >> 6] = ss;
        __syncthreads();
        if (tid == 0) {
            float s = red[0] + red[1] + red[2] + red[3];
            invn[row] = 1.0f / (sqrtf(s) + 1e-8f);
        }
    } else if (bid < 1024) {
        int r0 = (bid - 512) * 2;
#pragma unroll
        for (int rr = 0; rr < 2; rr++) {
            int row = r0 + rr;
            const float* x = emb + (size_t)row * E_;
            short* a = A2 + (size_t)row * (2 * E_);
#pragma unroll
            for (int j = 0; j < 4; j++) {
                int i = j * 256 + tid;
                float v = x[i];
                short h = f2bf(v);
                a[i] = h;
                a[E_ + i] = f2bf(v - bf2f(h));
            }
        }
    } else if (bid < 3072) {
        int b2 = bid - 1024;
        int c0 = (b2 & 31) * 32;   // over E (32 tiles)
        int r0 = (b2 >> 5) * 32;   // over D (64 tiles)
        transpose_split(fc1_w, Bt1, E_, r0, c0, 2 * D_, D_, tid, t);
    } else if (bid < 4096) {
        int b2 = bid - 3072;
        int c0 = (b2 & 31) * 32;   // over E
        int r0 = (b2 >> 5) * 32;   // over E
        transpose_split(fc2_w, Bt2, E_, r0, c0, 2 * E_, E_, tid, t);
    } else {
        int b2 = bid - 4096;
        int c0 = (b2 & 63) * 32;   // over D (64 tiles)
        int r0 = (b2 >> 6) * 32;   // over S (16 tiles)
        transpose_split(cf, cfT, D_, r0, c0, S_, 0, tid, t);
    }
}

// ---------------- 128x128 MFMA GEMM core, nt form, split-K ----------------
// P[z] = A(MxK)[kz:kz+Kc] @ B(NxK)[kz:kz+Kc]^T ; 4 waves, wave = 64x64
// double-buffered LDS (2 x 32KB), XOR-swizzled chunks, global_load_lds w=16.
struct GP {
    const short* A;
    const short* Bm;
    float* P;
    int M, N, K, Kc, nx, ny;
};

__device__ __forceinline__ void gemm128_core(const GP g, int bid, short* lds) {
    const int tid = threadIdx.x;
    const int per = g.nx * g.ny;
    const int z = bid / per, rem = bid % per;
    const int by = rem / g.nx, bx = rem % g.nx;
    const int bm = by * 128, bn = bx * 128;
    const int kz = z * g.Kc;
    float* C = g.P + (size_t)z * g.M * g.N;
    const short* gA = g.A + (size_t)bm * g.K + kz;
    const short* gB = g.Bm + (size_t)bn * g.K + kz;

    // per-thread staging offsets: chunks tid + i*256 of a 128x64 tile (1024 chunks)
    size_t soff[4];
#pragma unroll
    for (int i = 0; i < 4; i++) {
        int ci = tid + i * 256;
        int row = ci >> 3, c = ci & 7;
        soff[i] = (size_t)row * g.K + ((c ^ (row & 7)) << 3);
    }

    auto stage = [&](int buf, int kt) {
        short* base = lds + buf * 16384;
#pragma unroll
        for (int i = 0; i < 4; i++) {
            gload16(gA + soff[i] + kt, base + tid * 8 + i * 2048);
            gload16(gB + soff[i] + kt, base + 8192 + tid * 8 + i * 2048);
        }
    };

    const int lane = tid & 63, wid = tid >> 6;
    const int wr = wid >> 1, wc = wid & 1;
    const int r16 = lane & 15, kg = lane >> 4;
    const int rs7 = (r16 & 7);

    f32x4 acc[4][4] = {};
    const int nt = g.Kc >> 6;

    stage(0, 0);
    for (int t = 0; t < nt; ++t) {
        __syncthreads();
        if (t + 1 < nt) stage((t + 1) & 1, (t + 1) << 6);
        const short* LA = lds + (t & 1) * 16384;
        const short* LB = LA + 8192;
#pragma unroll
        for (int ks = 0; ks < 2; ++ks) {
            const int sw = ((ks * 4 + kg) ^ rs7) << 3;
            bf16x8 a[4], b[4];
#pragma unroll
            for (int m = 0; m < 4; m++)
                a[m] = *(const bf16x8*)(LA + (wr * 64 + m * 16 + r16) * 64 + sw);
#pragma unroll
            for (int n = 0; n < 4; n++)
                b[n] = *(const bf16x8*)(LB + (wc * 64 + n * 16 + r16) * 64 + sw);
#pragma unroll
            for (int m = 0; m < 4; m++)
#pragma unroll
                for (int n = 0; n < 4; n++)
                    acc[m][n] = __builtin_amdgcn_mfma_f32_16x16x32_bf16(a[m], b[n], acc[m][n], 0, 0, 0);
        }
    }

#pragma unroll
    for (int m = 0; m < 4; m++)
#pragma unroll
        for (int n = 0; n < 4; n++) {
            int col = bn + wc * 64 + n * 16 + r16;
#pragma unroll
            for (int r = 0; r < 4; r++) {
                int row = bm + wr * 64 + m * 16 + kg * 4 + r;
                C[(size_t)row * g.N + col] = acc[m][n][r];
            }
        }
}

__global__ __launch_bounds__(256) void gemm_dual(GP g0, GP g1, int n0) {
    __shared__ short lds[32768];
    int bid = blockIdx.x;
    if (bid < n0) gemm128_core(g0, bid, lds);
    else gemm128_core(g1, bid - n0, lds);
}

__global__ __launch_bounds__(256) void gemm_one(GP g) {
    __shared__ short lds[32768];
    gemm128_core(g, blockIdx.x, lds);
}

// ---------------- merged split-K reduce + BN partial stats (both branches) ----------------
// grid (4, 64): y<32 -> branch1 (S=512, KS=8); y>=32 -> branch2 (B=1024, KS=4)
__global__ __launch_bounds__(256) void bn_stats12(const float* __restrict__ P1,
                                                  const float* __restrict__ P2,
                                                  float* __restrict__ Z1,
                                                  float* __restrict__ Z2,
                                                  float* __restrict__ part1,
                                                  float* __restrict__ part2) {
    int c = blockIdx.x * 256 + threadIdx.x;
    if (blockIdx.y < 32) {
        int r0 = blockIdx.y * 16;
        float s = 0.f, ss = 0.f;
        for (int r = r0; r < r0 + 16; r++) {
            float z = 0.f;
#pragma unroll
            for (int k = 0; k < 8; k++) z += P1[(size_t)k * S_ * E_ + (size_t)r * E_ + c];
            Z1[(size_t)r * E_ + c] = z;
            s += z; ss += z * z;
        }
        part1[(size_t)blockIdx.y * 2 * E_ + c] = s;
        part1[(size_t)blockIdx.y * 2 * E_ + E_ + c] = ss;
    } else {
        int r0 = (blockIdx.y - 32) * 32;
        float s = 0.f, ss = 0.f;
        for (int r = r0; r < r0 + 32; r++) {
            float z = 0.f;
#pragma unroll
            for (int k = 0; k < 4; k++) z += P2[(size_t)k * B_ * E_ + (size_t)r * E_ + c];
            Z2[(size_t)r * E_ + c] = z;
            s += z; ss += z * z;
        }
        part2[(size_t)(blockIdx.y - 32) * 2 * E_ + c] = s;
        part2[(size_t)(blockIdx.y - 32) * 2 * E_ + E_ + c] = ss;
    }
}

// ---------------- merged BN finalize + tanh (+fc3 scale) -> concat-K bf16 pairs ----------------
// grid (4, 96): y<32 -> branch1 rows r0=y*16 of 512; y>=32 -> branch2 rows of 1024
__global__ __launch_bounds__(256) void bn_apply12(const float* __restrict__ Z1,
                                                  const float* __restrict__ Z2,
                                                  const float* __restrict__ part1,
                                                  const float* __restrict__ part2,
                                                  const float* __restrict__ g1,
                                                  const float* __restrict__ b1,
                                                  const float* __restrict__ g2,
                                                  const float* __restrict__ b2,
                                                  const float* __restrict__ fc3_w,
                                                  short* __restrict__ Ws,
                                                  short* __restrict__ Wv3) {
    int c = blockIdx.x * 256 + threadIdx.x;
    bool br1 = blockIdx.y < 32;
    const float* part = br1 ? part1 : part2;
    float s = 0.f, ss = 0.f;
#pragma unroll
    for (int k = 0; k < 32; k++) {
        s += part[(size_t)k * 2 * E_ + c];
        ss += part[(size_t)k * 2 * E_ + E_ + c];
    }
    float invR = br1 ? (1.0f / 512.0f) : (1.0f / 1024.0f);
    float mu = s * invR;
    float var = ss * invR - mu * mu;
    float rstd = rsqrtf(var + 1e-5f);
    float Aa = (br1 ? g1[c] : g2[c]) * rstd;
    float Bb = (br1 ? b1[c] : b2[c]) - Aa * mu;
    float sc = br1 ? 1.0f : fc3_w[c];
    const float* Z = br1 ? Z1 : Z2;
    short* W = br1 ? Ws : Wv3;
    int r0 = (br1 ? blockIdx.y : (blockIdx.y - 32)) * 16;
    for (int r = r0; r < r0 + 16; r++) {
        float w = tanhf(fmaf(Z[(size_t)r * E_ + c], Aa, Bb)) * sc;
        short h = f2bf(w);
        size_t o = (size_t)r * (2 * E_) + c;
        W[o] = h;
        W[o + E_] = f2bf(w - bf2f(h));
    }
}

// ---------------- split-K reduce + row softmax (n=512), fp32 out + invn-scaled bf16 ----------------
__global__ __launch_bounds__(256) void softmax_fused(const float* __restrict__ P, 
                                                     const float* __restrict__ invn,
                                                     float* __restrict__ O,
                                                     short* __restrict__ O16) {
    __shared__ float red[4];
    int row = blockIdx.x;
    int t = threadIdx.x;
    float v0 = 0.f, v1 = 0.f;
#pragma unroll
    for (int k = 0; k < 8; k++) {
        v0 += P[(size_t)k * B_ * S_ + (size_t)row * S_ + t];
        v1 += P[(size_t)k * B_ * S_ + (size_t)row * S_ + t + 256];
    }
    v0 *= SMOOTH;
    v1 *= SMOOTH;
    float m = waveReduceMax(fmaxf(v0, v1));
    if ((t & 63) == 0) red[t >> 6] = m;
    __syncthreads();
    m = fmaxf(fmaxf(red[0], red[1]), fmaxf(red[2], red[3]));
    float e0 = __expf(v0 - m), e1 = __expf(v1 - m);
    float s = waveReduceSum(e0 + e1);
    __syncthreads();
    if ((t & 63) == 0) red[t >> 6] = s;
    __syncthreads();
    s = red[0] + red[1] + red[2] + red[3];
    float inv = 1.0f / s;
    float w0 = e0 * inv, w1 = e1 * inv;
    O[(size_t)row * S_ + t] = w0;
    O[(size_t)row * S_ + t + 256] = w1;
    O16[(size_t)row * S_ + t] = f2bf(w0 * invn[t]);
    O16[(size_t)row * S_ + t + 256] = f2bf(w1 * invn[t + 256]);
}

// ---------------- reduce 2 split-K slices + row l2norm -> output ----------------
__global__ __launch_bounds__(256) void rownorm2(const float* __restrict__ P,
                                                float* __restrict__ O) {
    __shared__ float red[4];
    int row = blockIdx.x;
    int t = threadIdx.x;
    float v[8];
    float ss = 0.f;
#pragma unroll
    for (int j = 0; j < 8; j++) {
        size_t idx = (size_t)row * D_ + j * 256 + t;
        v[j] = P[idx] + P[(size_t)B_ * D_ + idx];
        ss += v[j] * v[j];
    }
    ss = waveReduceSum(ss);
    if ((t & 63) == 0) red[t >> 6] = ss;
    __syncthreads();
    ss = red[0] + red[1] + red[2] + red[3];
    float sc = 1.0f / (sqrtf(ss) + 1e-8f);
#pragma unroll
    for (int j = 0; j < 8; j++)
        O[(size_t)row * D_ + j * 256 + t] = v[j] * sc;
}

extern "C" void kernel_launch(void* const* d_in, const int* in_sizes, int n_in,
                              void* d_out, int out_size, void* d_ws, size_t ws_size,
                              hipStream_t stream) {
    const float* emb   = (const float*)d_in[0];   // (B,E)
    const float* cf    = (const float*)d_in[1];   // (S,D)
    const float* fc1_w = (const float*)d_in[3];   // (D,E)
    const float* bn1_g = (const float*)d_in[5];
    const float* bn1_b = (const float*)d_in[6];
    const float* fc2_w = (const float*)d_in[7];   // (E,E)
    const float* bn2_g = (const float*)d_in[9];
    const float* bn2_b = (const float*)d_in[10];
    const float* fc3_w = (const float*)d_in[11];  // (E,)

    float* out = (float*)d_out;
    float* emb_concept = out;                     // B*D
    float* weights_v   = out + (size_t)B_ * D_;   // B*S

    const size_t MB = 1024 * 1024;
    char* w = (char*)d_ws;
    short* Bt1  = (short*)(w + 0 * MB);           // 1024 x 4096 = 8MB
    short* A1   = (short*)(w + 8 * MB);           // 512 x 4096 = 4MB
    short* A2   = (short*)(w + 12 * MB);          // 1024 x 2048 = 4MB
    short* Bt2  = (short*)(w + 16 * MB);          // 1024 x 2048 = 4MB
    short* cfT  = (short*)(w + 20 * MB);          // 2048 x 512 = 2MB
    float* Z1   = (float*)(w + 22 * MB);          // 512 x 1024 = 2MB
    float* Z2   = (float*)(w + 24 * MB);          // 1024 x 1024 = 4MB
    short* Ws   = (short*)(w + 28 * MB);          // 512 x 2048 = 2MB
    short* Wv3  = (short*)(w + 30 * MB);          // 1024 x 2048 = 4MB
    short* A4   = (short*)(w + 34 * MB);          // 1024 x 512 = 1MB
    float* part1 = (float*)(w + 35 * MB);         // 32*2*E = 256KB
    float* part2 = (float*)(w + 36 * MB);         // 256KB
    float* invn  = (float*)(w + 37 * MB);         // S
    float* P1   = (float*)(w + 40 * MB);          // 8 x 512x1024 x4 = 16MB
    float* P2   = (float*)(w + 56 * MB);          // 4 x 1024x1024 x4 = 16MB
    float* P3   = (float*)(w + 40 * MB);          // 8 x 1024x512 x4 = 16MB (aliases P1, dead)
    float* P4   = (float*)(w + 56 * MB);          // 2 x 1024x2048 x4 = 16MB (aliases P2, dead)

    // 1. all conversions/transposes/invnorm in one kernel
    prep<<<5120, 256, 0, stream>>>(cf, emb, fc1_w, fc2_w, A1, invn, A2, Bt1, Bt2, cfT);

    // 2. G1 (512x1024x4096, KS=8) + G2 (1024x1024x2048, KS=4) in one 512-block launch
    GP g1 = {A1, Bt1, P1, S_, E_, 2 * D_, 512, 8, 4};
    GP g2 = {A2, Bt2, P2, B_, E_, 2 * E_, 512, 8, 8};
    gemm_dual<<<512, 256, 0, stream>>>(g1, g2, 256);

    // 3+4. BN both branches
    bn_stats12<<<dim3(4, 64), 256, 0, stream>>>(P1, P2, Z1, Z2, part1, part2);
    bn_apply12<<<dim3(4, 96), 256, 0, stream>>>(Z1, Z2, part1, part2, bn1_g, bn1_b,
                                                bn2_g, bn2_b, fc3_w, Ws, Wv3);

    // 5. G3: a_s partials = Wv3 @ Ws^T (1024x512x2048, KS=8)
    GP g3 = {Wv3, Ws, P3, B_, S_, 2 * E_, 256, 4, 8};
    gemm_one<<<256, 256, 0, stream>>>(g3);

    // 6. weights_v = softmax(sum_k P3 * SMOOTH); A4 = bf16(w * invn)
    softmax_fused<<<B_, 256, 0, stream>>>(P3, invn, weights_v, A4);

    // 7. G4: emb_pre partials = A4 @ cfT^T (1024x2048x512, KS=2, single bf16)
    GP g4 = {A4, cfT, P4, B_, D_, S_, 256, 16, 8};
    gemm_one<<<256, 256, 0, stream>>>(g4);

    // 8. emb_concept = l2norm(P4_0 + P4_1)
    rownorm2<<<B_, 256, 0, stream>>>(P4, emb_concept);
}

// Round 6
// 71.539 us; speedup vs baseline: 7.0691x; 1.0593x over previous
//
#include <hip/hip_runtime.h>
#include <hip/hip_bf16.h>
#include <math.h>

#define B_ 1024
#define S_ 512
#define E_ 1024
#define D_ 2048
#define SMOOTH 10.0f

typedef __attribute__((ext_vector_type(8))) short bf16x8;
typedef __attribute__((ext_vector_type(4))) float f32x4;

__device__ __forceinline__ short f2bf(float f) {
    __hip_bfloat16 h = __float2bfloat16(f);
    short s; __builtin_memcpy(&s, &h, 2); return s;
}
__device__ __forceinline__ float bf2f(short s) {
    __hip_bfloat16 h; __builtin_memcpy(&h, &s, 2);
    return __bfloat162float(h);
}

__device__ __forceinline__ void gload16(const short* g, short* l) {
    __builtin_amdgcn_global_load_lds(
        (const __attribute__((address_space(1))) void*)(g),
        (__attribute__((address_space(3))) void*)(l), 16, 0, 0);
}

__inline__ __device__ float waveReduceMax(float v) {
#pragma unroll
    for (int o = 32; o; o >>= 1) v = fmaxf(v, __shfl_xor(v, o));
    return v;
}
__inline__ __device__ float waveReduceSum(float v) {
#pragma unroll
    for (int o = 32; o; o >>= 1) v += __shfl_xor(v, o);
    return v;
}

// ---------------- transpose helper (32x32 tile via LDS) ----------------
__device__ __forceinline__ void transpose_split(const float* __restrict__ in,
                                                short* __restrict__ out,
                                                int C, int r0, int c0,
                                                int ldo, int loOff,
                                                int tid, float (*t)[33]) {
    int cx = tid & 31, ry0 = tid >> 5;
#pragma unroll
    for (int i = 0; i < 4; i++) {
        int ry = ry0 + i * 8;
        t[ry][cx] = in[(size_t)(r0 + ry) * C + c0 + cx];
    }
    __syncthreads();
    int rx = tid & 31, cy0 = tid >> 5;
#pragma unroll
    for (int i = 0; i < 4; i++) {
        int cy = cy0 + i * 8;
        float v = t[rx][cy];
        size_t o = (size_t)(c0 + cy) * ldo + r0 + rx;
        short h = f2bf(v);
        out[o] = h;
        if (loOff > 0) out[o + loOff] = f2bf(v - bf2f(h));
    }
}

// ---------------- fused preprocessing, blockIdx-segmented ----------------
__global__ __launch_bounds__(256) void prep(const float* __restrict__ cf,
                                            const float* __restrict__ emb,
                                            const float* __restrict__ fc1_w,
                                            const float* __restrict__ fc2_w,
                                            short* __restrict__ A1,
                                            float* __restrict__ invn,
                                            short* __restrict__ A2,
                                            short* __restrict__ Bt1,
                                            short* __restrict__ Bt2,
                                            short* __restrict__ cfT) {
    __shared__ float t[32][33];
    __shared__ float red[4];
    const int bid = blockIdx.x;
    const int tid = threadIdx.x;
    if (bid < 512) {
        int row = bid;
        const float* x = cf + (size_t)row * D_;
        short* a = A1 + (size_t)row * (2 * D_);
        float ss = 0.f;
#pragma unroll
        for (int j = 0; j < 8; j++) {
            int i = j * 256 + tid;
            float v = x[i];
            short h = f2bf(v);
            a[i] = h;
            a[D_ + i] = f2bf(v - bf2f(h));
            ss += v * v;
        }
        ss = waveReduceSum(ss);
        if ((tid & 63) == 0) red[tid >> 6] = ss;
        __syncthreads();
        if (tid == 0) {
            float s = red[0] + red[1] + red[2] + red[3];
            invn[row] = 1.0f / (sqrtf(s) + 1e-8f);
        }
    } else if (bid < 1024) {
        int r0 = (bid - 512) * 2;
#pragma unroll
        for (int rr = 0; rr < 2; rr++) {
            int row = r0 + rr;
            const float* x = emb + (size_t)row * E_;
            short* a = A2 + (size_t)row * (2 * E_);
#pragma unroll
            for (int j = 0; j < 4; j++) {
                int i = j * 256 + tid;
                float v = x[i];
                short h = f2bf(v);
                a[i] = h;
                a[E_ + i] = f2bf(v - bf2f(h));
            }
        }
    } else if (bid < 3072) {
        int b2 = bid - 1024;
        int c0 = (b2 & 31) * 32;
        int r0 = (b2 >> 5) * 32;
        transpose_split(fc1_w, Bt1, E_, r0, c0, 2 * D_, D_, tid, t);
    } else if (bid < 4096) {
        int b2 = bid - 3072;
        int c0 = (b2 & 31) * 32;
        int r0 = (b2 >> 5) * 32;
        transpose_split(fc2_w, Bt2, E_, r0, c0, 2 * E_, E_, tid, t);
    } else {
        int b2 = bid - 4096;
        int c0 = (b2 & 63) * 32;
        int r0 = (b2 >> 6) * 32;
        transpose_split(cf, cfT, D_, r0, c0, S_, 0, tid, t);
    }
}

// ---------------- 128x128 MFMA GEMM core, nt form, split-K ----------------
struct GP {
    const short* A;
    const short* Bm;
    float* P;
    int M, N, K, Kc, nx, ny;
};

__device__ __forceinline__ void gemm128_core(const GP g, int bid, short* lds) {
    const int tid = threadIdx.x;
    const int per = g.nx * g.ny;
    const int z = bid / per, rem = bid % per;
    const int by = rem / g.nx, bx = rem % g.nx;
    const int bm = by * 128, bn = bx * 128;
    const int kz = z * g.Kc;
    float* C = g.P + (size_t)z * g.M * g.N;
    const short* gA = g.A + (size_t)bm * g.K + kz;
    const short* gB = g.Bm + (size_t)bn * g.K + kz;

    size_t soff[4];
#pragma unroll
    for (int i = 0; i < 4; i++) {
        int ci = tid + i * 256;
        int row = ci >> 3, c = ci & 7;
        soff[i] = (size_t)row * g.K + ((c ^ (row & 7)) << 3);
    }

    auto stage = [&](int buf, int kt) {
        short* base = lds + buf * 16384;
#pragma unroll
        for (int i = 0; i < 4; i++) {
            gload16(gA + soff[i] + kt, base + tid * 8 + i * 2048);
            gload16(gB + soff[i] + kt, base + 8192 + tid * 8 + i * 2048);
        }
    };

    const int lane = tid & 63, wid = tid >> 6;
    const int wr = wid >> 1, wc = wid & 1;
    const int r16 = lane & 15, kg = lane >> 4;
    const int rs7 = (r16 & 7);

    f32x4 acc[4][4] = {};
    const int nt = g.Kc >> 6;

    stage(0, 0);
    for (int t = 0; t < nt; ++t) {
        __syncthreads();
        if (t + 1 < nt) stage((t + 1) & 1, (t + 1) << 6);
        const short* LA = lds + (t & 1) * 16384;
        const short* LB = LA + 8192;
#pragma unroll
        for (int ks = 0; ks < 2; ++ks) {
            const int sw = ((ks * 4 + kg) ^ rs7) << 3;
            bf16x8 a[4], b[4];
#pragma unroll
            for (int m = 0; m < 4; m++)
                a[m] = *(const bf16x8*)(LA + (wr * 64 + m * 16 + r16) * 64 + sw);
#pragma unroll
            for (int n = 0; n < 4; n++)
                b[n] = *(const bf16x8*)(LB + (wc * 64 + n * 16 + r16) * 64 + sw);
#pragma unroll
            for (int m = 0; m < 4; m++)
#pragma unroll
                for (int n = 0; n < 4; n++)
                    acc[m][n] = __builtin_amdgcn_mfma_f32_16x16x32_bf16(a[m], b[n], acc[m][n], 0, 0, 0);
        }
    }

#pragma unroll
    for (int m = 0; m < 4; m++)
#pragma unroll
        for (int n = 0; n < 4; n++) {
            int col = bn + wc * 64 + n * 16 + r16;
#pragma unroll
            for (int r = 0; r < 4; r++) {
                int row = bm + wr * 64 + m * 16 + kg * 4 + r;
                C[(size_t)row * g.N + col] = acc[m][n][r];
            }
        }
}

__global__ __launch_bounds__(256) void gemm_dual(GP g0, GP g1, int n0) {
    __shared__ short lds[32768];
    int bid = blockIdx.x;
    if (bid < n0) gemm128_core(g0, bid, lds);
    else gemm128_core(g1, bid - n0, lds);
}

__global__ __launch_bounds__(256) void gemm_one(GP g) {
    __shared__ short lds[32768];
    gemm128_core(g, blockIdx.x, lds);
}

// ---------------- merged split-K reduce + BN partial stats (both branches) ----------------
// grid (4, 64): y<32 -> branch1 (S=512, KS=4); y>=32 -> branch2 (B=1024, KS=2)
__global__ __launch_bounds__(256) void bn_stats12(const float* __restrict__ P1,
                                                  const float* __restrict__ P2,
                                                  float* __restrict__ Z1,
                                                  float* __restrict__ Z2,
                                                  float* __restrict__ part1,
                                                  float* __restrict__ part2) {
    int c = blockIdx.x * 256 + threadIdx.x;
    if (blockIdx.y < 32) {
        int r0 = blockIdx.y * 16;
        float s = 0.f, ss = 0.f;
        for (int r = r0; r < r0 + 16; r++) {
            float z = 0.f;
#pragma unroll
            for (int k = 0; k < 4; k++) z += P1[(size_t)k * S_ * E_ + (size_t)r * E_ + c];
            Z1[(size_t)r * E_ + c] = z;
            s += z; ss += z * z;
        }
        part1[(size_t)blockIdx.y * 2 * E_ + c] = s;
        part1[(size_t)blockIdx.y * 2 * E_ + E_ + c] = ss;
    } else {
        int r0 = (blockIdx.y - 32) * 32;
        float s = 0.f, ss = 0.f;
        for (int r = r0; r < r0 + 32; r++) {
            float z = 0.f;
#pragma unroll
            for (int k = 0; k < 2; k++) z += P2[(size_t)k * B_ * E_ + (size_t)r * E_ + c];
            Z2[(size_t)r * E_ + c] = z;
            s += z; ss += z * z;
        }
        part2[(size_t)(blockIdx.y - 32) * 2 * E_ + c] = s;
        part2[(size_t)(blockIdx.y - 32) * 2 * E_ + E_ + c] = ss;
    }
}

// ---------------- merged BN finalize + tanh (+fc3 scale) -> concat-K bf16 pairs ----------------
__global__ __launch_bounds__(256) void bn_apply12(const float* __restrict__ Z1,
                                                  const float* __restrict__ Z2,
                                                  const float* __restrict__ part1,
                                                  const float* __restrict__ part2,
                                                  const float* __restrict__ g1,
                                                  const float* __restrict__ b1,
                                                  const float* __restrict__ g2,
                                                  const float* __restrict__ b2,
                                                  const float* __restrict__ fc3_w,
                                                  short* __restrict__ Ws,
                                                  short* __restrict__ Wv3) {
    int c = blockIdx.x * 256 + threadIdx.x;
    bool br1 = blockIdx.y < 32;
    const float* part = br1 ? part1 : part2;
    float s = 0.f, ss = 0.f;
#pragma unroll
    for (int k = 0; k < 32; k++) {
        s += part[(size_t)k * 2 * E_ + c];
        ss += part[(size_t)k * 2 * E_ + E_ + c];
    }
    float invR = br1 ? (1.0f / 512.0f) : (1.0f / 1024.0f);
    float mu = s * invR;
    float var = ss * invR - mu * mu;
    float rstd = rsqrtf(var + 1e-5f);
    float Aa = (br1 ? g1[c] : g2[c]) * rstd;
    float Bb = (br1 ? b1[c] : b2[c]) - Aa * mu;
    float sc = br1 ? 1.0f : fc3_w[c];
    const float* Z = br1 ? Z1 : Z2;
    short* W = br1 ? Ws : Wv3;
    int r0 = (br1 ? blockIdx.y : (blockIdx.y - 32)) * 16;
    for (int r = r0; r < r0 + 16; r++) {
        float w = tanhf(fmaf(Z[(size_t)r * E_ + c], Aa, Bb)) * sc;
        short h = f2bf(w);
        size_t o = (size_t)r * (2 * E_) + c;
        W[o] = h;
        W[o + E_] = f2bf(w - bf2f(h));
    }
}

// ---------------- split-K reduce (KS=4) + row softmax, fp32 out + invn-scaled bf16 ----------------
__global__ __launch_bounds__(256) void softmax_fused(const float* __restrict__ P,
                                                     const float* __restrict__ invn,
                                                     float* __restrict__ O,
                                                     short* __restrict__ O16) {
    __shared__ float red[4];
    int row = blockIdx.x;
    int t = threadIdx.x;
    float v0 = 0.f, v1 = 0.f;
#pragma unroll
    for (int k = 0; k < 4; k++) {
        v0 += P[(size_t)k * B_ * S_ + (size_t)row * S_ + t];
        v1 += P[(size_t)k * B_ * S_ + (size_t)row * S_ + t + 256];
    }
    v0 *= SMOOTH;
    v1 *= SMOOTH;
    float m = waveReduceMax(fmaxf(v0, v1));
    if ((t & 63) == 0) red[t >> 6] = m;
    __syncthreads();
    m = fmaxf(fmaxf(red[0], red[1]), fmaxf(red[2], red[3]));
    float e0 = __expf(v0 - m), e1 = __expf(v1 - m);
    float s = waveReduceSum(e0 + e1);
    __syncthreads();
    if ((t & 63) == 0) red[t >> 6] = s;
    __syncthreads();
    s = red[0] + red[1] + red[2] + red[3];
    float inv = 1.0f / s;
    float w0 = e0 * inv, w1 = e1 * inv;
    O[(size_t)row * S_ + t] = w0;
    O[(size_t)row * S_ + t + 256] = w1;
    O16[(size_t)row * S_ + t] = f2bf(w0 * invn[t]);
    O16[(size_t)row * S_ + t + 256] = f2bf(w1 * invn[t + 256]);
}

// ---------------- row l2norm (single slice) -> output ----------------
__global__ __launch_bounds__(256) void rownorm1(const float* __restrict__ P,
                                                float* __restrict__ O) {
    __shared__ float red[4];
    int row = blockIdx.x;
    int t = threadIdx.x;
    float v[8];
    float ss = 0.f;
#pragma unroll
    for (int j = 0; j < 8; j++) {
        v[j] = P[(size_t)row * D_ + j * 256 + t];
        ss += v[j] * v[j];
    }
    ss = waveReduceSum(ss);
    if ((t & 63) == 0) red[t >> 6] = ss;
    __syncthreads();
    ss = red[0] + red[1] + red[2] + red[3];
    float sc = 1.0f / (sqrtf(ss) + 1e-8f);
#pragma unroll
    for (int j = 0; j < 8; j++)
        O[(size_t)row * D_ + j * 256 + t] = v[j] * sc;
}

extern "C" void kernel_launch(void* const* d_in, const int* in_sizes, int n_in,
                              void* d_out, int out_size, void* d_ws, size_t ws_size,
                              hipStream_t stream) {
    const float* emb   = (const float*)d_in[0];   // (B,E)
    const float* cf    = (const float*)d_in[1];   // (S,D)
    const float* fc1_w = (const float*)d_in[3];   // (D,E)
    const float* bn1_g = (const float*)d_in[5];
    const float* bn1_b = (const float*)d_in[6];
    const float* fc2_w = (const float*)d_in[7];   // (E,E)
    const float* bn2_g = (const float*)d_in[9];
    const float* bn2_b = (const float*)d_in[10];
    const float* fc3_w = (const float*)d_in[11];  // (E,)

    float* out = (float*)d_out;
    float* emb_concept = out;                     // B*D
    float* weights_v   = out + (size_t)B_ * D_;   // B*S

    const size_t MB = 1024 * 1024;
    char* w = (char*)d_ws;
    short* Bt1  = (short*)(w + 0 * MB);           // 1024 x 4096 = 8MB
    short* A1   = (short*)(w + 8 * MB);           // 512 x 4096 = 4MB
    short* A2   = (short*)(w + 12 * MB);          // 1024 x 2048 = 4MB
    short* Bt2  = (short*)(w + 16 * MB);          // 1024 x 2048 = 4MB
    short* cfT  = (short*)(w + 20 * MB);          // 2048 x 512 = 2MB
    float* Z1   = (float*)(w + 22 * MB);          // 512 x 1024 = 2MB
    float* Z2   = (float*)(w + 24 * MB);          // 1024 x 1024 = 4MB
    short* Ws   = (short*)(w + 28 * MB);          // 512 x 2048 = 2MB
    short* Wv3  = (short*)(w + 30 * MB);          // 1024 x 2048 = 4MB
    short* A4   = (short*)(w + 34 * MB);          // 1024 x 512 = 1MB
    float* part1 = (float*)(w + 35 * MB);         // 32*2*E = 256KB
    float* part2 = (float*)(w + 36 * MB);         // 256KB
    float* invn  = (float*)(w + 37 * MB);         // S
    float* P1   = (float*)(w + 40 * MB);          // 4 x 512x1024 x4 = 8MB
    float* P2   = (float*)(w + 48 * MB);          // 2 x 1024x1024 x4 = 8MB
    float* P3   = (float*)(w + 40 * MB);          // 4 x 1024x512 x4 = 8MB (aliases P1, dead)
    float* emb_pre = (float*)(w + 48 * MB);       // 1024x2048 x4 = 8MB (aliases P2, dead)

    // 1. all conversions/transposes/invnorm in one kernel
    prep<<<5120, 256, 0, stream>>>(cf, emb, fc1_w, fc2_w, A1, invn, A2, Bt1, Bt2, cfT);

    // 2. G1 (512x1024x4096, KS=4) + G2 (1024x1024x2048, KS=2) in one 256-block launch
    GP g1 = {A1, Bt1, P1, S_, E_, 2 * D_, 1024, 8, 4};
    GP g2 = {A2, Bt2, P2, B_, E_, 2 * E_, 1024, 8, 8};
    gemm_dual<<<256, 256, 0, stream>>>(g1, g2, 128);

    // 3+4. BN both branches
    bn_stats12<<<dim3(4, 64), 256, 0, stream>>>(P1, P2, Z1, Z2, part1, part2);
    bn_apply12<<<dim3(4, 96), 256, 0, stream>>>(Z1, Z2, part1, part2, bn1_g, bn1_b,
                                                bn2_g, bn2_b, fc3_w, Ws, Wv3);

    // 5. G3: a_s partials = Wv3 @ Ws^T (1024x512x2048, KS=4)
    GP g3 = {Wv3, Ws, P3, B_, S_, 2 * E_, 512, 4, 8};
    gemm_one<<<128, 256, 0, stream>>>(g3);

    // 6. weights_v = softmax(sum_k P3 * SMOOTH); A4 = bf16(w * invn)
    softmax_fused<<<B_, 256, 0, stream>>>(P3, invn, weights_v, A4);

    // 7. G4: emb_pre = A4 @ cfT^T (1024x2048x512, KS=1, single bf16)
    GP g4 = {A4, cfT, emb_pre, B_, D_, S_, 512, 16, 8};
    gemm_one<<<128, 256, 0, stream>>>(g4);

    // 8. emb_concept = l2norm(emb_pre)
    rownorm1<<<B_, 256, 0, stream>>>(emb_pre, emb_concept);
}